// Round 14
// baseline (704.541 us; speedup 1.0000x reference)
//
#include <hip/hip_runtime.h>
#include <hip/hip_bf16.h>

typedef __attribute__((ext_vector_type(8))) short short8v;
typedef __attribute__((ext_vector_type(4))) float floatx4;

__device__ __forceinline__ float bf2f(unsigned short u) {
  union { unsigned int i; float f; } c;
  c.i = ((unsigned int)u) << 16;
  return c.f;
}
__device__ __forceinline__ unsigned short f2bf(float f) {
  __hip_bfloat16 h = __float2bfloat16(f);
  return *reinterpret_cast<unsigned short*>(&h);
}

// ---------------------------------------------------------------------------
// Fused conversion: 9 jobs fp32 -> bf16.
// ---------------------------------------------------------------------------
struct ConvJobs {
  const float* src[9];
  unsigned short* dst[9];
  int K[9];
  int Kp[9];
  int mode[9];
  int cum[10];
};

__global__ __launch_bounds__(256) void convert_all_kernel(ConvJobs J) {
  const int total = J.cum[9];
  for (int idx = blockIdx.x * 256 + threadIdx.x; idx < total;
       idx += gridDim.x * 256) {
    int j = 0;
    while (idx >= J.cum[j + 1]) ++j;
    const int local = idx - J.cum[j];
    const int Kp = J.Kp[j];
    const int r = local / Kp, c = local - r * Kp;
    unsigned short v;
    if (J.mode[j] == 0) {
      v = (c < J.K[j]) ? f2bf(J.src[j][(size_t)r * J.K[j] + c])
                       : (unsigned short)0;
    } else {
      const int h = c >> 5, d = c & 31;
      v = (d < 29) ? f2bf(J.src[j][(size_t)r * 116 + h * 29 + d])
                   : (unsigned short)0;
    }
    J.dst[j][local] = v;
  }
}

// ---------------------------------------------------------------------------
// qkv GEMM: grid (M/128, 3).  Coalesced head-major epilogue via LDS restage.
// Output qkvp[which][(n*4+h)*64+s][32] bf16.
// ---------------------------------------------------------------------------
__global__ __launch_bounds__(256) void qkv_gemm_kernel(
    const unsigned short* __restrict__ A,  // bf16 [32768][128]
    const unsigned short* __restrict__ B,  // bf16 [348][128] (wqkv)
    const float* __restrict__ bias,        // [348]
    unsigned short* __restrict__ qkvp) {
  __shared__ __align__(16) unsigned char shmem[32768];
  unsigned short (*As)[64] = reinterpret_cast<unsigned short(*)[64]>(shmem);
  unsigned short (*Bs)[64] =
      reinterpret_cast<unsigned short(*)[64]>(shmem + 16384);
  unsigned short (*Qt)[120] = reinterpret_cast<unsigned short(*)[120]>(shmem);

  const int tid = threadIdx.x;
  const int M0 = blockIdx.x * 128;
  const int which = blockIdx.y;  // 0..2
  const int wid = tid >> 6, lane = tid & 63;
  const int wr = wid >> 1, wc = wid & 1;
  const int lc = lane & 15, g = lane >> 4;
  const int srow = tid >> 1, shalf = tid & 1;
  const int sw = srow & 7;

  floatx4 acc[4][4] = {};

  for (int kt = 0; kt < 2; ++kt) {
    const int k0 = kt << 6;
    {
      const uint4* p = reinterpret_cast<const uint4*>(
          A + (size_t)(M0 + srow) * 128 + k0 + shalf * 32);
      uint4 v0 = p[0], v1 = p[1], v2 = p[2], v3 = p[3];
      *reinterpret_cast<uint4*>(&As[srow][((((shalf << 2) | 0) ^ sw) << 3)]) = v0;
      *reinterpret_cast<uint4*>(&As[srow][((((shalf << 2) | 1) ^ sw) << 3)]) = v1;
      *reinterpret_cast<uint4*>(&As[srow][((((shalf << 2) | 2) ^ sw) << 3)]) = v2;
      *reinterpret_cast<uint4*>(&As[srow][((((shalf << 2) | 3) ^ sw) << 3)]) = v3;
    }
    {
      uint4 v0 = {0, 0, 0, 0}, v1 = v0, v2 = v0, v3 = v0;
      if (srow < 116) {
        const uint4* p = reinterpret_cast<const uint4*>(
            B + (size_t)(which * 116 + srow) * 128 + k0 + shalf * 32);
        v0 = p[0]; v1 = p[1]; v2 = p[2]; v3 = p[3];
      }
      *reinterpret_cast<uint4*>(&Bs[srow][((((shalf << 2) | 0) ^ sw) << 3)]) = v0;
      *reinterpret_cast<uint4*>(&Bs[srow][((((shalf << 2) | 1) ^ sw) << 3)]) = v1;
      *reinterpret_cast<uint4*>(&Bs[srow][((((shalf << 2) | 2) ^ sw) << 3)]) = v2;
      *reinterpret_cast<uint4*>(&Bs[srow][((((shalf << 2) | 3) ^ sw) << 3)]) = v3;
    }
    __syncthreads();
#pragma unroll
    for (int ks = 0; ks < 2; ++ks) {
      short8v a[4], b[4];
#pragma unroll
      for (int m = 0; m < 4; ++m) {
        const int row = wr * 64 + m * 16 + lc;
        a[m] = *reinterpret_cast<const short8v*>(
            &As[row][((((ks << 2) | g) ^ (lc & 7)) << 3)]);
      }
#pragma unroll
      for (int n = 0; n < 4; ++n) {
        const int col = wc * 64 + n * 16 + lc;
        b[n] = *reinterpret_cast<const short8v*>(
            &Bs[col][((((ks << 2) | g) ^ (lc & 7)) << 3)]);
      }
#pragma unroll
      for (int m = 0; m < 4; ++m)
#pragma unroll
        for (int n = 0; n < 4; ++n)
          acc[m][n] = __builtin_amdgcn_mfma_f32_16x16x32_bf16(a[m], b[n],
                                                              acc[m][n], 0, 0, 0);
    }
    __syncthreads();
  }

#pragma unroll
  for (int m = 0; m < 4; ++m) {
#pragma unroll
    for (int r = 0; r < 4; ++r) {
      const int lrow = wr * 64 + m * 16 + g * 4 + r;
#pragma unroll
      for (int n = 0; n < 4; ++n) {
        const int col = wc * 64 + n * 16 + lc;
        if (col < 116)
          Qt[lrow][col] = f2bf(acc[m][n][r] + bias[which * 116 + col]);
      }
    }
  }
  __syncthreads();

  const int s_idx = M0 >> 9;
  const int nbase = M0 & 511;
  for (int idx = tid; idx < 2048; idx += 256) {
    const int dg = idx & 3, h = (idx >> 2) & 3, n = idx >> 4;
    unsigned short ow[8];
#pragma unroll
    for (int j = 0; j < 8; ++j) {
      const int d = dg * 8 + j;
      ow[j] = (d < 29) ? Qt[n][h * 29 + d] : (unsigned short)0;
    }
    uint4* dst = reinterpret_cast<uint4*>(
        qkvp + (size_t)which * 4194304 +
        ((((size_t)(nbase + n) * 4 + h) * 64 + s_idx) << 5) + dg * 8);
    *dst = *reinterpret_cast<const uint4*>(ow);
  }
}

// ---------------------------------------------------------------------------
// 64-row-tile GEMM + residual + LayerNorm (N=116).  Used for o-proj (K=128).
// ---------------------------------------------------------------------------
__global__ __launch_bounds__(256) void mgemm64_ln_kernel(
    const unsigned short* __restrict__ A, const unsigned short* __restrict__ B,
    const float* __restrict__ bias, int Kp, unsigned short* __restrict__ Yb,
    float* __restrict__ Yf, const float* __restrict__ res,
    const float* __restrict__ gw, const float* __restrict__ bw) {
  __shared__ __align__(16) unsigned short As[64][64];
  __shared__ __align__(16) unsigned short Bs[128][64];
  __shared__ float sum1[2][64];
  __shared__ float sum2[2][64];

  const int tid = threadIdx.x;
  const int M0 = blockIdx.x * 64;
  const int wid = tid >> 6, lane = tid & 63;
  const int wr = wid >> 1, wc = wid & 1;
  const int lc = lane & 15, g = lane >> 4;
  const int arow = tid >> 2, aq = tid & 3;
  const int brow = tid >> 1, bhalf = tid & 1;

  floatx4 acc[2][4] = {};

  const int nk = Kp >> 6;
  for (int kt = 0; kt < nk; ++kt) {
    const int k0 = kt << 6;
    {
      const uint4* p = reinterpret_cast<const uint4*>(
          A + (size_t)(M0 + arow) * Kp + k0 + aq * 16);
      uint4 v0 = p[0], v1 = p[1];
      const int swa = arow & 7;
      *reinterpret_cast<uint4*>(&As[arow][(((aq * 2) ^ swa) << 3)]) = v0;
      *reinterpret_cast<uint4*>(&As[arow][(((aq * 2 + 1) ^ swa) << 3)]) = v1;
    }
    {
      uint4 v0 = {0, 0, 0, 0}, v1 = v0, v2 = v0, v3 = v0;
      if (brow < 116) {
        const uint4* p = reinterpret_cast<const uint4*>(
            B + (size_t)brow * Kp + k0 + bhalf * 32);
        v0 = p[0]; v1 = p[1]; v2 = p[2]; v3 = p[3];
      }
      const int sw = brow & 7;
      *reinterpret_cast<uint4*>(&Bs[brow][((((bhalf << 2) | 0) ^ sw) << 3)]) = v0;
      *reinterpret_cast<uint4*>(&Bs[brow][((((bhalf << 2) | 1) ^ sw) << 3)]) = v1;
      *reinterpret_cast<uint4*>(&Bs[brow][((((bhalf << 2) | 2) ^ sw) << 3)]) = v2;
      *reinterpret_cast<uint4*>(&Bs[brow][((((bhalf << 2) | 3) ^ sw) << 3)]) = v3;
    }
    __syncthreads();
#pragma unroll
    for (int ks = 0; ks < 2; ++ks) {
      short8v a[2], b[4];
#pragma unroll
      for (int m = 0; m < 2; ++m) {
        const int row = wr * 32 + m * 16 + lc;
        a[m] = *reinterpret_cast<const short8v*>(
            &As[row][((((ks << 2) | g) ^ (row & 7)) << 3)]);
      }
#pragma unroll
      for (int n = 0; n < 4; ++n) {
        const int col = wc * 64 + n * 16 + lc;
        b[n] = *reinterpret_cast<const short8v*>(
            &Bs[col][((((ks << 2) | g) ^ (col & 7)) << 3)]);
      }
#pragma unroll
      for (int m = 0; m < 2; ++m)
#pragma unroll
        for (int n = 0; n < 4; ++n)
          acc[m][n] = __builtin_amdgcn_mfma_f32_16x16x32_bf16(a[m], b[n],
                                                              acc[m][n], 0, 0, 0);
    }
    __syncthreads();
  }

  float s1l[2][4], s2l[2][4];
#pragma unroll
  for (int m = 0; m < 2; ++m) {
#pragma unroll
    for (int r = 0; r < 4; ++r) {
      const int row = M0 + wr * 32 + m * 16 + g * 4 + r;
      float s = 0.f, s2 = 0.f;
#pragma unroll
      for (int n = 0; n < 4; ++n) {
        const int col = wc * 64 + n * 16 + lc;
        float v = 0.f;
        if (col < 116)
          v = acc[m][n][r] + bias[col] + res[(size_t)row * 116 + col];
        acc[m][n][r] = v;
        s += v;
        s2 = fmaf(v, v, s2);
      }
#pragma unroll
      for (int st = 1; st < 16; st <<= 1) {
        s += __shfl_xor(s, st, 16);
        s2 += __shfl_xor(s2, st, 16);
      }
      s1l[m][r] = s;
      s2l[m][r] = s2;
    }
  }
  if (lc == 0) {
#pragma unroll
    for (int m = 0; m < 2; ++m)
#pragma unroll
      for (int r = 0; r < 4; ++r) {
        const int lrow = wr * 32 + m * 16 + g * 4 + r;
        sum1[wc][lrow] = s1l[m][r];
        sum2[wc][lrow] = s2l[m][r];
      }
  }
  __syncthreads();
#pragma unroll
  for (int m = 0; m < 2; ++m) {
#pragma unroll
    for (int r = 0; r < 4; ++r) {
      const int lrow = wr * 32 + m * 16 + g * 4 + r;
      const int row = M0 + lrow;
      const float st = sum1[0][lrow] + sum1[1][lrow];
      const float s2t = sum2[0][lrow] + sum2[1][lrow];
      const float mean = st * (1.f / 116.f);
      const float var = s2t * (1.f / 116.f) - mean * mean;
      const float rstd = 1.f / sqrtf(var + 1e-5f);
#pragma unroll
      for (int n = 0; n < 4; ++n) {
        const int col = wc * 64 + n * 16 + lc;
        if (col < 116) {
          const float y = (acc[m][n][r] - mean) * rstd * gw[col] + bw[col];
          Yf[(size_t)row * 116 + col] = y;
          Yb[(size_t)row * 128 + col] = f2bf(y);
        } else {
          Yb[(size_t)row * 128 + col] = 0;
        }
      }
    }
  }
}

// ---------------------------------------------------------------------------
// Fused FFN v4: weights read DIRECTLY from global (L2-resident) as MFMA
// B-fragments — no W LDS staging.  64-token tile, dff chunk 128, 256 thr /
// 4 waves (wr: tok-half, wc: col-half), 2 blocks/CU.  Only Xs + Hs in LDS.
// out = LayerNorm(res + relu(Xa @ W1^T + b1) @ W2^T + b2)
// ---------------------------------------------------------------------------
__global__ __launch_bounds__(256, 2) void ffn_fused4_kernel(
    const unsigned short* __restrict__ Xa,  // bf16 [32768][128]
    const unsigned short* __restrict__ W1,  // bf16 [2048][128]
    const float* __restrict__ b1,
    const unsigned short* __restrict__ W2,  // bf16 [116][2048]
    const float* __restrict__ b2, const float* __restrict__ res,
    const float* __restrict__ gw, const float* __restrict__ bw,
    unsigned short* __restrict__ Yb,  // bf16 [32768][128]
    float* __restrict__ Yf) {         // fp32 [32768][116]
  __shared__ __align__(16) unsigned short Xs[64][128];  // 16 KB swizzled
  __shared__ __align__(16) unsigned short Hs[64][136];  // 17 KB padded
  __shared__ float sum1[2][64];
  __shared__ float sum2[2][64];

  const int tid = threadIdx.x;
  const int M0 = blockIdx.x * 64;
  const int wid = tid >> 6, lane = tid & 63;
  const int wr = wid >> 1, wc = wid & 1;
  const int lc = lane & 15, g = lane >> 4;
  const int arow = tid >> 2, aq = tid & 3;

  // stage Xs once (swz = (cj&8) | ((cj^row)&7))
  {
    const uint4* p = reinterpret_cast<const uint4*>(
        Xa + (size_t)(M0 + arow) * 128 + aq * 32);
#pragma unroll
    for (int q = 0; q < 4; ++q) {
      const int cj = aq * 4 + q;
      const int swz = (cj & 8) | ((cj ^ arow) & 7);
      *reinterpret_cast<uint4*>(&Xs[arow][swz * 8]) = p[q];
    }
  }
  __syncthreads();

  floatx4 oacc[2][4] = {};

  for (int kc = 0; kc < 16; ++kc) {
    // ---- h = Xs @ W1chunk^T (64 tok x 128 dff; this wave: wc half) ----
    floatx4 hacc[2][4] = {};
#pragma unroll
    for (int ks = 0; ks < 4; ++ks) {
      short8v av[2], bv[4];
      const int cj = ks * 4 + g;
#pragma unroll
      for (int m = 0; m < 2; ++m) {
        const int row = wr * 32 + m * 16 + lc;
        const int swz = (cj & 8) | ((cj ^ row) & 7);
        av[m] = *reinterpret_cast<const short8v*>(&Xs[row][swz * 8]);
      }
#pragma unroll
      for (int n = 0; n < 4; ++n) {
        const int dffrow = kc * 128 + wc * 64 + n * 16 + lc;
        bv[n] = *reinterpret_cast<const short8v*>(
            W1 + (size_t)dffrow * 128 + ks * 32 + g * 8);
      }
#pragma unroll
      for (int m = 0; m < 2; ++m)
#pragma unroll
        for (int n = 0; n < 4; ++n)
          hacc[m][n] = __builtin_amdgcn_mfma_f32_16x16x32_bf16(av[m], bv[n],
                                                               hacc[m][n], 0, 0, 0);
    }
    // relu + b1 -> Hs
#pragma unroll
    for (int n = 0; n < 4; ++n) {
      const int dff = wc * 64 + n * 16 + lc;
      const float bb = b1[kc * 128 + dff];
#pragma unroll
      for (int m = 0; m < 2; ++m) {
#pragma unroll
        for (int r = 0; r < 4; ++r) {
          const int tok = wr * 32 + m * 16 + g * 4 + r;
          Hs[tok][dff] = f2bf(fmaxf(hacc[m][n][r] + bb, 0.f));
        }
      }
    }
    __syncthreads();

    // ---- oacc += Hs @ W2chunk^T (K=128) ----
#pragma unroll
    for (int ks = 0; ks < 4; ++ks) {
      short8v av[2], bv[4];
      const int cj = ks * 4 + g;
#pragma unroll
      for (int m = 0; m < 2; ++m) {
        const int row = wr * 32 + m * 16 + lc;
        av[m] = *reinterpret_cast<const short8v*>(&Hs[row][cj * 8]);
      }
#pragma unroll
      for (int n = 0; n < 4; ++n) {
        const int e = wc * 64 + n * 16 + lc;
        if (e < 116) {
          bv[n] = *reinterpret_cast<const short8v*>(
              W2 + (size_t)e * 2048 + kc * 128 + ks * 32 + g * 8);
        } else {
          bv[n] = short8v{0, 0, 0, 0, 0, 0, 0, 0};
        }
      }
#pragma unroll
      for (int m = 0; m < 2; ++m)
#pragma unroll
        for (int n = 0; n < 4; ++n)
          oacc[m][n] = __builtin_amdgcn_mfma_f32_16x16x32_bf16(av[m], bv[n],
                                                               oacc[m][n], 0, 0, 0);
    }
    __syncthreads();  // Hs reused next chunk
  }

  // residual + LayerNorm epilogue
  float s1l[2][4], s2l[2][4];
#pragma unroll
  for (int m = 0; m < 2; ++m) {
#pragma unroll
    for (int r = 0; r < 4; ++r) {
      const int row = M0 + wr * 32 + m * 16 + g * 4 + r;
      float s = 0.f, s2 = 0.f;
#pragma unroll
      for (int n = 0; n < 4; ++n) {
        const int col = wc * 64 + n * 16 + lc;
        float v = 0.f;
        if (col < 116)
          v = oacc[m][n][r] + b2[col] + res[(size_t)row * 116 + col];
        oacc[m][n][r] = v;
        s += v;
        s2 = fmaf(v, v, s2);
      }
#pragma unroll
      for (int st = 1; st < 16; st <<= 1) {
        s += __shfl_xor(s, st, 16);
        s2 += __shfl_xor(s2, st, 16);
      }
      s1l[m][r] = s;
      s2l[m][r] = s2;
    }
  }
  if (lc == 0) {
#pragma unroll
    for (int m = 0; m < 2; ++m)
#pragma unroll
      for (int r = 0; r < 4; ++r) {
        const int lrow = wr * 32 + m * 16 + g * 4 + r;
        sum1[wc][lrow] = s1l[m][r];
        sum2[wc][lrow] = s2l[m][r];
      }
  }
  __syncthreads();
#pragma unroll
  for (int m = 0; m < 2; ++m) {
#pragma unroll
    for (int r = 0; r < 4; ++r) {
      const int lrow = wr * 32 + m * 16 + g * 4 + r;
      const int row = M0 + lrow;
      const float st = sum1[0][lrow] + sum1[1][lrow];
      const float s2t = sum2[0][lrow] + sum2[1][lrow];
      const float mean = st * (1.f / 116.f);
      const float var = s2t * (1.f / 116.f) - mean * mean;
      const float rstd = 1.f / sqrtf(var + 1e-5f);
#pragma unroll
      for (int n = 0; n < 4; ++n) {
        const int col = wc * 64 + n * 16 + lc;
        if (col < 116) {
          const float y = (oacc[m][n][r] - mean) * rstd * gw[col] + bw[col];
          Yf[(size_t)row * 116 + col] = y;
          Yb[(size_t)row * 128 + col] = f2bf(y);
        } else {
          Yb[(size_t)row * 128 + col] = 0;
        }
      }
    }
  }
}

// ---------------------------------------------------------------------------
// Attention, head-major coalesced I/O.
// ---------------------------------------------------------------------------
__global__ __launch_bounds__(64) void attn_kernel(
    const unsigned short* __restrict__ qkvp, unsigned short* __restrict__ obuf) {
  const int h = blockIdx.x & 3;
  const int n = blockIdx.x >> 2;
  const int s = threadIdx.x;
  __shared__ float ks[64][36];
  __shared__ float vs[64][36];

  const size_t rb = (((size_t)n * 4 + h) * 64 + s) * 32;
  const uint4* qp = reinterpret_cast<const uint4*>(qkvp + rb);
  const uint4* kp = reinterpret_cast<const uint4*>(qkvp + 4194304 + rb);
  const uint4* vp = reinterpret_cast<const uint4*>(qkvp + 8388608 + rb);
  uint4 qv[4], kv4[4], vv4[4];
#pragma unroll
  for (int i = 0; i < 4; ++i) {
    qv[i] = qp[i];
    kv4[i] = kp[i];
    vv4[i] = vp[i];
  }
  float q[32], kf[32], vf[32];
#pragma unroll
  for (int i = 0; i < 4; ++i) {
    const unsigned* wq = reinterpret_cast<const unsigned*>(&qv[i]);
    const unsigned* wk = reinterpret_cast<const unsigned*>(&kv4[i]);
    const unsigned* wv = reinterpret_cast<const unsigned*>(&vv4[i]);
#pragma unroll
    for (int j = 0; j < 4; ++j) {
      union { unsigned u; float f; } lo, hi;
      const int d0 = i * 8 + 2 * j;
      lo.u = wq[j] << 16; hi.u = wq[j] & 0xffff0000u;
      q[d0] = lo.f; q[d0 + 1] = hi.f;
      lo.u = wk[j] << 16; hi.u = wk[j] & 0xffff0000u;
      kf[d0] = (d0 < 29) ? lo.f : 0.f;
      kf[d0 + 1] = (d0 + 1 < 29) ? hi.f : 0.f;
      lo.u = wv[j] << 16; hi.u = wv[j] & 0xffff0000u;
      vf[d0] = (d0 < 29) ? lo.f : 0.f;
      vf[d0 + 1] = (d0 + 1 < 29) ? hi.f : 0.f;
    }
  }
  q[29] = q[30] = q[31] = 0.f;
#pragma unroll
  for (int c = 0; c < 8; ++c) {
    *reinterpret_cast<float4*>(&ks[s][c * 4]) =
        make_float4(kf[4 * c], kf[4 * c + 1], kf[4 * c + 2], kf[4 * c + 3]);
    *reinterpret_cast<float4*>(&vs[s][c * 4]) =
        make_float4(vf[4 * c], vf[4 * c + 1], vf[4 * c + 2], vf[4 * c + 3]);
  }
  __syncthreads();

  const float scale = 0.18569533817705186f;  // 1/sqrt(29)
  float sc[64];
#pragma unroll 4
  for (int t = 0; t < 64; ++t) {
    const float4* kr = reinterpret_cast<const float4*>(&ks[t][0]);
    float a = 0.f;
#pragma unroll
    for (int c = 0; c < 8; ++c) {
      const float4 kc = kr[c];
      a = fmaf(q[4 * c], kc.x, a);
      a = fmaf(q[4 * c + 1], kc.y, a);
      a = fmaf(q[4 * c + 2], kc.z, a);
      a = fmaf(q[4 * c + 3], kc.w, a);
    }
    sc[t] = a * scale;
  }
  float m = sc[0];
#pragma unroll
  for (int t = 1; t < 64; ++t) m = fmaxf(m, sc[t]);
  float sum = 0.f;
#pragma unroll
  for (int t = 0; t < 64; ++t) {
    sc[t] = __expf(sc[t] - m);
    sum += sc[t];
  }
  const float inv = 1.f / sum;
  float o[32] = {};
#pragma unroll 4
  for (int t = 0; t < 64; ++t) {
    const float p = sc[t];
    const float4* vr = reinterpret_cast<const float4*>(&vs[t][0]);
#pragma unroll
    for (int c = 0; c < 8; ++c) {
      const float4 vc = vr[c];
      o[4 * c] = fmaf(p, vc.x, o[4 * c]);
      o[4 * c + 1] = fmaf(p, vc.y, o[4 * c + 1]);
      o[4 * c + 2] = fmaf(p, vc.z, o[4 * c + 2]);
      o[4 * c + 3] = fmaf(p, vc.w, o[4 * c + 3]);
    }
  }
  unsigned short ow[32];
#pragma unroll
  for (int i = 0; i < 32; ++i) ow[i] = f2bf(o[i] * inv);
  uint4* od =
      reinterpret_cast<uint4*>(obuf + ((size_t)s * 512 + n) * 128 + h * 32);
  const uint4* ows = reinterpret_cast<const uint4*>(ow);
#pragma unroll
  for (int i = 0; i < 4; ++i) od[i] = ows[i];
}

// ---------------------------------------------------------------------------
// fc fused with feaT/fn production.
// ---------------------------------------------------------------------------
__global__ __launch_bounds__(256) void fc_kernel(
    const float* __restrict__ X4, const float* __restrict__ fw,
    const float* __restrict__ fb, float* __restrict__ fea,
    unsigned short* __restrict__ feaT, float* __restrict__ fn) {
  const int eg = blockIdx.x;  // 0..3
  const int b = blockIdx.y;   // 0..63
  const int e0 = eg * 29;
  __shared__ float Os[64][30];
  __shared__ float Wf[64][65];
  const int tid = threadIdx.x;
  const int h = tid & 63, jg = tid >> 6;
  float acc[8] = {};

  for (int tc = 0; tc < 8; ++tc) {
    for (int idx = tid; idx < 64 * 29; idx += 256) {
      int tt = idx / 29;
      int ee = idx - tt * 29;
      Os[tt][ee] = X4[((size_t)b * 512 + tc * 64 + tt) * 116 + e0 + ee];
    }
    for (int idx = tid; idx < 64 * 64; idx += 256) {
      int hh = idx >> 6, t2 = idx & 63;
      Wf[hh][t2] = fw[(size_t)hh * 512 + tc * 64 + t2];
    }
    __syncthreads();
#pragma unroll 4
    for (int t = 0; t < 64; ++t) {
      const float w = Wf[h][t];
#pragma unroll
      for (int m = 0; m < 8; ++m) {
        const int el = jg + 4 * m;
        if (el < 29) acc[m] = fmaf(Os[t][el], w, acc[m]);
      }
    }
    __syncthreads();
  }
  const float bb = fb[h];
#pragma unroll
  for (int m = 0; m < 8; ++m) {
    const int el = jg + 4 * m;
    if (el < 29) {
      const float v = acc[m] + bb;
      const int e = e0 + el;
      fea[((size_t)b * 64 + h) * 116 + e] = v;
      if (feaT) {
        const unsigned short vb = f2bf(v);
        feaT[((size_t)b * 128 + e) * 64 + h] = vb;
        float s = bf2f(vb);
        s = s * s;
#pragma unroll
        for (int st = 1; st <= 32; st <<= 1) s += __shfl_xor(s, st, 64);
        if (h == 0) fn[b * 128 + e] = sqrtf(s);
      }
    }
  }
}

// ---------------------------------------------------------------------------
// simT prep: simT[a][c(96)][h(64)] bf16, sn[a][96].
// ---------------------------------------------------------------------------
__global__ __launch_bounds__(256) void simt_prep_kernel(
    const float* __restrict__ simin, unsigned short* __restrict__ simT,
    float* __restrict__ sn) {
  __shared__ float L[64][91];
  const int a = blockIdx.x;
  const int tid = threadIdx.x;
  for (int idx = tid; idx < 64 * 90; idx += 256) {
    const int h = idx / 90, c = idx - h * 90;
    L[h][c] = bf2f(f2bf(simin[((size_t)a * 64 + h) * 90 + c]));
  }
  __syncthreads();
  for (int idx = tid; idx < 96 * 64; idx += 256) {
    const int c = idx >> 6, h = idx & 63;
    simT[((size_t)a * 96 + c) * 64 + h] = (c < 90) ? f2bf(L[h][c]) : 0;
  }
  if (tid < 90) {
    float s = 0.f;
#pragma unroll 8
    for (int h = 0; h < 64; ++h) {
      const float t = L[h][tid];
      s = fmaf(t, t, s);
    }
    sn[a * 96 + tid] = sqrtf(s);
  }
}

// ---------------------------------------------------------------------------
// Similarity v3: block = (b, 4 consecutive a's).
// ---------------------------------------------------------------------------
__global__ __launch_bounds__(256) void sim_mfma3_kernel(
    const unsigned short* __restrict__ feaT, const unsigned short* __restrict__ simT,
    const float* __restrict__ fn, const float* __restrict__ sn,
    float* __restrict__ simil, float* __restrict__ similar) {
  const int a0 = blockIdx.x * 4;  // 0,4,...,112
  const int b = blockIdx.y;       // 0..63
  __shared__ __align__(16) unsigned short Ft[128][64];
  __shared__ __align__(16) unsigned short St[96][64];
  __shared__ __align__(16) float Rs[10440];
  __shared__ float fnrow[116];
  __shared__ float snrow[90];
  __shared__ float wred[4];
  const int tid = threadIdx.x;
  const int srow = tid >> 1, shalf = tid & 1;
  const int sw = srow & 7;
  const int wid = tid >> 6, lane = tid & 63;
  const int wr = wid >> 1, wc = wid & 1;
  const int lc = lane & 15, g = lane >> 4;

  {
    const uint4* p = reinterpret_cast<const uint4*>(
        feaT + ((size_t)b * 128 + srow) * 64 + shalf * 32);
    uint4 v0 = p[0], v1 = p[1], v2 = p[2], v3 = p[3];
    *reinterpret_cast<uint4*>(&Ft[srow][((((shalf << 2) | 0) ^ sw) << 3)]) = v0;
    *reinterpret_cast<uint4*>(&Ft[srow][((((shalf << 2) | 1) ^ sw) << 3)]) = v1;
    *reinterpret_cast<uint4*>(&Ft[srow][((((shalf << 2) | 2) ^ sw) << 3)]) = v2;
    *reinterpret_cast<uint4*>(&Ft[srow][((((shalf << 2) | 3) ^ sw) << 3)]) = v3;
  }
  if (tid < 116) fnrow[tid] = fn[b * 128 + tid];

  for (int ai = 0; ai < 4; ++ai) {
    const int a = a0 + ai;
    if (srow < 96) {
      const uint4* p = reinterpret_cast<const uint4*>(
          simT + ((size_t)a * 96 + srow) * 64 + shalf * 32);
      uint4 v0 = p[0], v1 = p[1], v2 = p[2], v3 = p[3];
      *reinterpret_cast<uint4*>(&St[srow][((((shalf << 2) | 0) ^ sw) << 3)]) = v0;
      *reinterpret_cast<uint4*>(&St[srow][((((shalf << 2) | 1) ^ sw) << 3)]) = v1;
      *reinterpret_cast<uint4*>(&St[srow][((((shalf << 2) | 2) ^ sw) << 3)]) = v2;
      *reinterpret_cast<uint4*>(&St[srow][((((shalf << 2) | 3) ^ sw) << 3)]) = v3;
    }
    if (tid >= 160 && tid < 250) snrow[tid - 160] = sn[a * 96 + (tid - 160)];
    __syncthreads();

    floatx4 acc[4][3] = {};
#pragma unroll
    for (int ks = 0; ks < 2; ++ks) {
      short8v av[4], bv[3];
#pragma unroll
      for (int m = 0; m < 4; ++m) {
        const int row = wr * 64 + m * 16 + lc;
        av[m] = *reinterpret_cast<const short8v*>(
            &Ft[row][((((ks << 2) | g) ^ (lc & 7)) << 3)]);
      }
#pragma unroll
      for (int n = 0; n < 3; ++n) {
        const int col = wc * 48 + n * 16 + lc;
        bv[n] = *reinterpret_cast<const short8v*>(
            &St[col][((((ks << 2) | g) ^ (lc & 7)) << 3)]);
      }
#pragma unroll
      for (int m = 0; m < 4; ++m)
#pragma unroll
        for (int n = 0; n < 3; ++n)
          acc[m][n] = __builtin_amdgcn_mfma_f32_16x16x32_bf16(av[m], bv[n],
                                                              acc[m][n], 0, 0, 0);
    }

    float ss = 0.f;
#pragma unroll
    for (int m = 0; m < 4; ++m) {
#pragma unroll
      for (int r = 0; r < 4; ++r) {
        const int d = wr * 64 + m * 16 + g * 4 + r;
        if (d < 116) {
          const float fnv = fnrow[d];
#pragma unroll
          for (int n = 0; n < 3; ++n) {
            const int c = wc * 48 + n * 16 + lc;
            if (c < 90) {
              const float denom = fmaxf(fnv * snrow[c], 1e-8f);
              float rcp = __builtin_amdgcn_rcpf(denom);
              rcp = rcp * (2.0f - denom * rcp);
              const float v = acc[m][n][r] * rcp;
              ss = fmaf(v, v, ss);
              Rs[d * 90 + c] = v;
            }
          }
        }
      }
    }
#pragma unroll
    for (int st = 1; st <= 32; st <<= 1) ss += __shfl_xor(ss, st, 64);
    if (lane == 0) wred[wid] = ss;
    __syncthreads();
    const float tot = wred[0] + wred[1] + wred[2] + wred[3];
    const float inv = 1.f / fmaxf(sqrtf(tot), 1e-12f);

    const size_t rowbase = ((size_t)b * 116 + a) * (116 * 90);
    float4* so = reinterpret_cast<float4*>(simil + rowbase);
    float4* sr = reinterpret_cast<float4*>(similar + rowbase);
    const float4* rs4 = reinterpret_cast<const float4*>(Rs);
    for (int i = tid; i < 2610; i += 256) {
      float4 v = rs4[i];
      so[i] = v;
      float4 w;
      w.x = v.x * inv; w.y = v.y * inv; w.z = v.z * inv; w.w = v.w * inv;
      sr[i] = w;
    }
  }
}

// ---------------------------------------------------------------------------
// Fallback similarity (self-contained) if d_ws is too small.
// ---------------------------------------------------------------------------
__global__ __launch_bounds__(256) void sim_mfma_kernel(
    const float* __restrict__ fea, const float* __restrict__ simin,
    float* __restrict__ simil, float* __restrict__ similar) {
  const int a = blockIdx.x;
  const int b = blockIdx.y;
  __shared__ __align__(16) unsigned char shmem[41760];
  __shared__ float fnrow[116];
  __shared__ float snrow[90];
  __shared__ float wred[4];
  const int tid = threadIdx.x;

  unsigned short (*Ft)[64] = reinterpret_cast<unsigned short(*)[64]>(shmem);
  unsigned short (*St)[64] =
      reinterpret_cast<unsigned short(*)[64]>(shmem + 16384);
  float* Rs = reinterpret_cast<float*>(shmem);

  for (int idx = tid; idx < 64 * 116; idx += 256) {
    const int h = idx / 116, d = idx - h * 116;
    Ft[d][(((h >> 3) ^ (d & 7)) << 3) | (h & 7)] =
        f2bf(fea[((size_t)b * 64 + h) * 116 + d]);
  }
  for (int idx = tid; idx < 12 * 64; idx += 256) {
    const int d = 116 + (idx >> 6), h = idx & 63;
    Ft[d][(((h >> 3) ^ (d & 7)) << 3) | (h & 7)] = 0;
  }
  for (int idx = tid; idx < 64 * 90; idx += 256) {
    const int h = idx / 90, c = idx - h * 90;
    St[c][(((h >> 3) ^ (c & 7)) << 3) | (h & 7)] =
        f2bf(simin[((size_t)a * 64 + h) * 90 + c]);
  }
  for (int idx = tid; idx < 6 * 64; idx += 256) {
    const int c = 90 + (idx >> 6), h = idx & 63;
    St[c][(((h >> 3) ^ (c & 7)) << 3) | (h & 7)] = 0;
  }
  __syncthreads();

  if (tid < 116) {
    float s = 0.f;
#pragma unroll 8
    for (int h = 0; h < 64; ++h) {
      const float t = bf2f(Ft[tid][(((h >> 3) ^ (tid & 7)) << 3) | (h & 7)]);
      s = fmaf(t, t, s);
    }
    fnrow[tid] = sqrtf(s);
  } else if (tid >= 128 && tid < 218) {
    const int c = tid - 128;
    float s = 0.f;
#pragma unroll 8
    for (int h = 0; h < 64; ++h) {
      const float t = bf2f(St[c][(((h >> 3) ^ (c & 7)) << 3) | (h & 7)]);
      s = fmaf(t, t, s);
    }
    snrow[c] = sqrtf(s);
  }
  __syncthreads();

  const int wid = tid >> 6, lane = tid & 63;
  const int wr = wid >> 1, wc = wid & 1;
  const int lc = lane & 15, g = lane >> 4;

  floatx4 acc[4][3] = {};
#pragma unroll
  for (int ks = 0; ks < 2; ++ks) {
    short8v av[4], bv[3];
#pragma unroll
    for (int m = 0; m < 4; ++m) {
      const int row = wr * 64 + m * 16 + lc;
      av[m] = *reinterpret_cast<const short8v*>(
          &Ft[row][((((ks << 2) | g) ^ (lc & 7)) << 3)]);
    }
#pragma unroll
    for (int n = 0; n < 3; ++n) {
      const int col = wc * 48 + n * 16 + lc;
      bv[n] = *reinterpret_cast<const short8v*>(
          &St[col][((((ks << 2) | g) ^ (lc & 7)) << 3)]);
    }
#pragma unroll
    for (int m = 0; m < 4; ++m)
#pragma unroll
      for (int n = 0; n < 3; ++n)
        acc[m][n] = __builtin_amdgcn_mfma_f32_16x16x32_bf16(av[m], bv[n],
                                                            acc[m][n], 0, 0, 0);
  }
  __syncthreads();

  float ss = 0.f;
#pragma unroll
  for (int m = 0; m < 4; ++m) {
#pragma unroll
    for (int r = 0; r < 4; ++r) {
      const int d = wr * 64 + m * 16 + g * 4 + r;
      if (d < 116) {
        const float fnv = fnrow[d];
#pragma unroll
        for (int n = 0; n < 3; ++n) {
          const int c = wc * 48 + n * 16 + lc;
          if (c < 90) {
            const float denom = fmaxf(fnv * snrow[c], 1e-8f);
            float rcp = __builtin_amdgcn_rcpf(denom);
            rcp = rcp * (2.0f - denom * rcp);
            const float v = acc[m][n][r] * rcp;
            ss = fmaf(v, v, ss);
            Rs[d * 90 + c] = v;
          }
        }
      }
    }
  }
#pragma unroll
  for (int st = 1; st <= 32; st <<= 1) ss += __shfl_xor(ss, st, 64);
  if (lane == 0) wred[wid] = ss;
  __syncthreads();
  const float tot = wred[0] + wred[1] + wred[2] + wred[3];
  const float inv = 1.f / fmaxf(sqrtf(tot), 1e-12f);

  const size_t rowbase = ((size_t)b * 116 + a) * (116 * 90);
  float4* so = reinterpret_cast<float4*>(simil + rowbase);
  float4* sr = reinterpret_cast<float4*>(similar + rowbase);
  const float4* rs4 = reinterpret_cast<const float4*>(Rs);
  for (int i = tid; i < 2610; i += 256) {
    float4 v = rs4[i];
    so[i] = v;
    float4 w;
    w.x = v.x * inv; w.y = v.y * inv; w.z = v.z * inv; w.w = v.w * inv;
    sr[i] = w;
  }
}

// ---------------------------------------------------------------------------
extern "C" void kernel_launch(void* const* d_in, const int* in_sizes, int n_in,
                              void* d_out, int out_size, void* d_ws,
                              size_t ws_size, hipStream_t stream) {
  const float* x0 = (const float*)d_in[0];
  const float* simin = (const float*)d_in[1];
  const float* p[24];
  for (int i = 0; i < 24; ++i) p[i] = (const float*)d_in[2 + i];
  const float* fc_w = (const float*)d_in[26];
  const float* fc_b = (const float*)d_in[27];

  float* out = (float*)d_out;
  float* fea = out;
  float* simil = out + 475136;       // 77,506,560 floats
  float* similar = out + 77981696;   // 475136 + 77506560

  // scratch in 'similar' region (all dead before sim writes it):
  float* xa_f[2] = {similar + 0, similar + 7602176};
  float* xb_f[2] = {similar + 3801088, similar + 11403264};
  unsigned short* obufb = (unsigned short*)(similar + 15204352);
  unsigned short* qkvp = (unsigned short*)(similar + 17301504);
  unsigned short* Ab = (unsigned short*)(similar + 23592960);
  unsigned short* xab[2] = {(unsigned short*)(similar + 25690112),
                            (unsigned short*)(similar + 29884416)};
  unsigned short* xbb[2] = {(unsigned short*)(similar + 27787264),
                            (unsigned short*)(similar + 31981568)};
  // scratch in 'simil' region:
  unsigned short* wbuf = (unsigned short*)(simil + 33554432);
  const size_t WSZ = 559104;

  // d_ws layout for sim (bytes)
  unsigned char* ws = (unsigned char*)d_ws;
  unsigned short* feaT = (unsigned short*)ws;                   // 1,048,576 B
  unsigned short* simT = (unsigned short*)(ws + 1048576);       // 1,425,408 B
  float* fnb = (float*)(ws + 2473984);
  float* snb = (float*)(ws + 2506752);
  const bool ws_ok = ws_size >= 2551296;

  {
    ConvJobs J;
    int cum = 0;
    auto add = [&](int j, const float* s, unsigned short* dd, int R, int K,
                   int Kp, int mode) {
      J.src[j] = s; J.dst[j] = dd; J.K[j] = K; J.Kp[j] = Kp; J.mode[j] = mode;
      J.cum[j] = cum; cum += R * Kp;
    };
    add(0, x0, Ab, 32768, 116, 128, 0);
    for (int L = 0; L < 2; ++L) {
      unsigned short* wb = wbuf + L * WSZ;
      add(1 + L * 4, p[L * 12 + 0], wb + 0, 348, 116, 128, 0);
      add(2 + L * 4, p[L * 12 + 2], wb + 44544, 116, 116, 128, 1);
      add(3 + L * 4, p[L * 12 + 6], wb + 59392, 2048, 116, 128, 0);
      add(4 + L * 4, p[L * 12 + 8], wb + 321536, 116, 2048, 2048, 0);
    }
    J.cum[9] = cum;
    hipLaunchKernelGGL(convert_all_kernel, dim3(2048), dim3(256), 0, stream, J);
  }

  if (ws_ok) {
    hipLaunchKernelGGL(simt_prep_kernel, dim3(116), dim3(256), 0, stream,
                       simin, simT, snb);
  }

  const unsigned short* Ain = Ab;
  const float* resin = x0;
  for (int L = 0; L < 2; ++L) {
    unsigned short* wb = wbuf + L * WSZ;
    const float* bqkv = p[L * 12 + 1];
    const float* bo = p[L * 12 + 3];
    const float* g1 = p[L * 12 + 4];
    const float* bn1 = p[L * 12 + 5];
    const float* b1 = p[L * 12 + 7];
    const float* b2 = p[L * 12 + 9];
    const float* g2 = p[L * 12 + 10];
    const float* bn2 = p[L * 12 + 11];

    hipLaunchKernelGGL(qkv_gemm_kernel, dim3(256, 3), dim3(256), 0, stream,
                       Ain, wb + 0, bqkv, qkvp);
    hipLaunchKernelGGL(attn_kernel, dim3(2048), dim3(64), 0, stream, qkvp,
                       obufb);
    hipLaunchKernelGGL(mgemm64_ln_kernel, dim3(512), dim3(256), 0, stream,
                       obufb, wb + 44544, bo, 128, xab[L], xa_f[L], resin, g1,
                       bn1);
    // fused FFN v4: weights direct-from-L2, only Xs+Hs in LDS, 2 blocks/CU
    hipLaunchKernelGGL(ffn_fused4_kernel, dim3(512), dim3(256), 0, stream,
                       xab[L], wb + 59392, b1, wb + 321536, b2, xa_f[L], g2,
                       bn2, xbb[L], xb_f[L]);
    Ain = xbb[L];
    resin = xb_f[L];
  }

  if (ws_ok) {
    hipLaunchKernelGGL(fc_kernel, dim3(4, 64), dim3(256), 0, stream, xb_f[1],
                       fc_w, fc_b, fea, feaT, fnb);
    hipLaunchKernelGGL(sim_mfma3_kernel, dim3(29, 64), dim3(256), 0, stream,
                       feaT, simT, fnb, snb, simil, similar);
  } else {
    hipLaunchKernelGGL(fc_kernel, dim3(4, 64), dim3(256), 0, stream, xb_f[1],
                       fc_w, fc_b, fea, (unsigned short*)nullptr,
                       (float*)nullptr);
    hipLaunchKernelGGL(sim_mfma_kernel, dim3(116, 64), dim3(256), 0, stream,
                       fea, simin, simil, similar);
  }
}

// Round 15
// 608.976 us; speedup vs baseline: 1.1569x; 1.1569x over previous
//
#include <hip/hip_runtime.h>
#include <hip/hip_bf16.h>

typedef __attribute__((ext_vector_type(8))) short short8v;
typedef __attribute__((ext_vector_type(4))) float floatx4;

__device__ __forceinline__ float bf2f(unsigned short u) {
  union { unsigned int i; float f; } c;
  c.i = ((unsigned int)u) << 16;
  return c.f;
}
__device__ __forceinline__ unsigned short f2bf(float f) {
  __hip_bfloat16 h = __float2bfloat16(f);
  return *reinterpret_cast<unsigned short*>(&h);
}

// ---------------------------------------------------------------------------
// Fused conversion: 9 jobs fp32 -> bf16.
// ---------------------------------------------------------------------------
struct ConvJobs {
  const float* src[9];
  unsigned short* dst[9];
  int K[9];
  int Kp[9];
  int mode[9];
  int cum[10];
};

__global__ __launch_bounds__(256) void convert_all_kernel(ConvJobs J) {
  const int total = J.cum[9];
  for (int idx = blockIdx.x * 256 + threadIdx.x; idx < total;
       idx += gridDim.x * 256) {
    int j = 0;
    while (idx >= J.cum[j + 1]) ++j;
    const int local = idx - J.cum[j];
    const int Kp = J.Kp[j];
    const int r = local / Kp, c = local - r * Kp;
    unsigned short v;
    if (J.mode[j] == 0) {
      v = (c < J.K[j]) ? f2bf(J.src[j][(size_t)r * J.K[j] + c])
                       : (unsigned short)0;
    } else {
      const int h = c >> 5, d = c & 31;
      v = (d < 29) ? f2bf(J.src[j][(size_t)r * 116 + h * 29 + d])
                   : (unsigned short)0;
    }
    J.dst[j][local] = v;
  }
}

// ---------------------------------------------------------------------------
// qkv GEMM: grid (M/128, 3).  Coalesced head-major epilogue via LDS restage.
// Output qkvp[which][(n*4+h)*64+s][32] bf16.
// ---------------------------------------------------------------------------
__global__ __launch_bounds__(256) void qkv_gemm_kernel(
    const unsigned short* __restrict__ A,  // bf16 [32768][128]
    const unsigned short* __restrict__ B,  // bf16 [348][128] (wqkv)
    const float* __restrict__ bias,        // [348]
    unsigned short* __restrict__ qkvp) {
  __shared__ __align__(16) unsigned char shmem[32768];
  unsigned short (*As)[64] = reinterpret_cast<unsigned short(*)[64]>(shmem);
  unsigned short (*Bs)[64] =
      reinterpret_cast<unsigned short(*)[64]>(shmem + 16384);
  unsigned short (*Qt)[120] = reinterpret_cast<unsigned short(*)[120]>(shmem);

  const int tid = threadIdx.x;
  const int M0 = blockIdx.x * 128;
  const int which = blockIdx.y;  // 0..2
  const int wid = tid >> 6, lane = tid & 63;
  const int wr = wid >> 1, wc = wid & 1;
  const int lc = lane & 15, g = lane >> 4;
  const int srow = tid >> 1, shalf = tid & 1;
  const int sw = srow & 7;

  floatx4 acc[4][4] = {};

  for (int kt = 0; kt < 2; ++kt) {
    const int k0 = kt << 6;
    {
      const uint4* p = reinterpret_cast<const uint4*>(
          A + (size_t)(M0 + srow) * 128 + k0 + shalf * 32);
      uint4 v0 = p[0], v1 = p[1], v2 = p[2], v3 = p[3];
      *reinterpret_cast<uint4*>(&As[srow][((((shalf << 2) | 0) ^ sw) << 3)]) = v0;
      *reinterpret_cast<uint4*>(&As[srow][((((shalf << 2) | 1) ^ sw) << 3)]) = v1;
      *reinterpret_cast<uint4*>(&As[srow][((((shalf << 2) | 2) ^ sw) << 3)]) = v2;
      *reinterpret_cast<uint4*>(&As[srow][((((shalf << 2) | 3) ^ sw) << 3)]) = v3;
    }
    {
      uint4 v0 = {0, 0, 0, 0}, v1 = v0, v2 = v0, v3 = v0;
      if (srow < 116) {
        const uint4* p = reinterpret_cast<const uint4*>(
            B + (size_t)(which * 116 + srow) * 128 + k0 + shalf * 32);
        v0 = p[0]; v1 = p[1]; v2 = p[2]; v3 = p[3];
      }
      *reinterpret_cast<uint4*>(&Bs[srow][((((shalf << 2) | 0) ^ sw) << 3)]) = v0;
      *reinterpret_cast<uint4*>(&Bs[srow][((((shalf << 2) | 1) ^ sw) << 3)]) = v1;
      *reinterpret_cast<uint4*>(&Bs[srow][((((shalf << 2) | 2) ^ sw) << 3)]) = v2;
      *reinterpret_cast<uint4*>(&Bs[srow][((((shalf << 2) | 3) ^ sw) << 3)]) = v3;
    }
    __syncthreads();
#pragma unroll
    for (int ks = 0; ks < 2; ++ks) {
      short8v a[4], b[4];
#pragma unroll
      for (int m = 0; m < 4; ++m) {
        const int row = wr * 64 + m * 16 + lc;
        a[m] = *reinterpret_cast<const short8v*>(
            &As[row][((((ks << 2) | g) ^ (lc & 7)) << 3)]);
      }
#pragma unroll
      for (int n = 0; n < 4; ++n) {
        const int col = wc * 64 + n * 16 + lc;
        b[n] = *reinterpret_cast<const short8v*>(
            &Bs[col][((((ks << 2) | g) ^ (lc & 7)) << 3)]);
      }
#pragma unroll
      for (int m = 0; m < 4; ++m)
#pragma unroll
        for (int n = 0; n < 4; ++n)
          acc[m][n] = __builtin_amdgcn_mfma_f32_16x16x32_bf16(a[m], b[n],
                                                              acc[m][n], 0, 0, 0);
    }
    __syncthreads();
  }

#pragma unroll
  for (int m = 0; m < 4; ++m) {
#pragma unroll
    for (int r = 0; r < 4; ++r) {
      const int lrow = wr * 64 + m * 16 + g * 4 + r;
#pragma unroll
      for (int n = 0; n < 4; ++n) {
        const int col = wc * 64 + n * 16 + lc;
        if (col < 116)
          Qt[lrow][col] = f2bf(acc[m][n][r] + bias[which * 116 + col]);
      }
    }
  }
  __syncthreads();

  const int s_idx = M0 >> 9;
  const int nbase = M0 & 511;
  for (int idx = tid; idx < 2048; idx += 256) {
    const int dg = idx & 3, h = (idx >> 2) & 3, n = idx >> 4;
    unsigned short ow[8];
#pragma unroll
    for (int j = 0; j < 8; ++j) {
      const int d = dg * 8 + j;
      ow[j] = (d < 29) ? Qt[n][h * 29 + d] : (unsigned short)0;
    }
    uint4* dst = reinterpret_cast<uint4*>(
        qkvp + (size_t)which * 4194304 +
        ((((size_t)(nbase + n) * 4 + h) * 64 + s_idx) << 5) + dg * 8);
    *dst = *reinterpret_cast<const uint4*>(ow);
  }
}

// ---------------------------------------------------------------------------
// 64-row-tile GEMM + residual + LayerNorm (N=116).  Used for o-proj (K=128).
// ---------------------------------------------------------------------------
__global__ __launch_bounds__(256) void mgemm64_ln_kernel(
    const unsigned short* __restrict__ A, const unsigned short* __restrict__ B,
    const float* __restrict__ bias, int Kp, unsigned short* __restrict__ Yb,
    float* __restrict__ Yf, const float* __restrict__ res,
    const float* __restrict__ gw, const float* __restrict__ bw) {
  __shared__ __align__(16) unsigned short As[64][64];
  __shared__ __align__(16) unsigned short Bs[128][64];
  __shared__ float sum1[2][64];
  __shared__ float sum2[2][64];

  const int tid = threadIdx.x;
  const int M0 = blockIdx.x * 64;
  const int wid = tid >> 6, lane = tid & 63;
  const int wr = wid >> 1, wc = wid & 1;
  const int lc = lane & 15, g = lane >> 4;
  const int arow = tid >> 2, aq = tid & 3;
  const int brow = tid >> 1, bhalf = tid & 1;

  floatx4 acc[2][4] = {};

  const int nk = Kp >> 6;
  for (int kt = 0; kt < nk; ++kt) {
    const int k0 = kt << 6;
    {
      const uint4* p = reinterpret_cast<const uint4*>(
          A + (size_t)(M0 + arow) * Kp + k0 + aq * 16);
      uint4 v0 = p[0], v1 = p[1];
      const int swa = arow & 7;
      *reinterpret_cast<uint4*>(&As[arow][(((aq * 2) ^ swa) << 3)]) = v0;
      *reinterpret_cast<uint4*>(&As[arow][(((aq * 2 + 1) ^ swa) << 3)]) = v1;
    }
    {
      uint4 v0 = {0, 0, 0, 0}, v1 = v0, v2 = v0, v3 = v0;
      if (brow < 116) {
        const uint4* p = reinterpret_cast<const uint4*>(
            B + (size_t)brow * Kp + k0 + bhalf * 32);
        v0 = p[0]; v1 = p[1]; v2 = p[2]; v3 = p[3];
      }
      const int sw = brow & 7;
      *reinterpret_cast<uint4*>(&Bs[brow][((((bhalf << 2) | 0) ^ sw) << 3)]) = v0;
      *reinterpret_cast<uint4*>(&Bs[brow][((((bhalf << 2) | 1) ^ sw) << 3)]) = v1;
      *reinterpret_cast<uint4*>(&Bs[brow][((((bhalf << 2) | 2) ^ sw) << 3)]) = v2;
      *reinterpret_cast<uint4*>(&Bs[brow][((((bhalf << 2) | 3) ^ sw) << 3)]) = v3;
    }
    __syncthreads();
#pragma unroll
    for (int ks = 0; ks < 2; ++ks) {
      short8v a[2], b[4];
#pragma unroll
      for (int m = 0; m < 2; ++m) {
        const int row = wr * 32 + m * 16 + lc;
        a[m] = *reinterpret_cast<const short8v*>(
            &As[row][((((ks << 2) | g) ^ (row & 7)) << 3)]);
      }
#pragma unroll
      for (int n = 0; n < 4; ++n) {
        const int col = wc * 64 + n * 16 + lc;
        b[n] = *reinterpret_cast<const short8v*>(
            &Bs[col][((((ks << 2) | g) ^ (col & 7)) << 3)]);
      }
#pragma unroll
      for (int m = 0; m < 2; ++m)
#pragma unroll
        for (int n = 0; n < 4; ++n)
          acc[m][n] = __builtin_amdgcn_mfma_f32_16x16x32_bf16(a[m], b[n],
                                                              acc[m][n], 0, 0, 0);
    }
    __syncthreads();
  }

  float s1l[2][4], s2l[2][4];
#pragma unroll
  for (int m = 0; m < 2; ++m) {
#pragma unroll
    for (int r = 0; r < 4; ++r) {
      const int row = M0 + wr * 32 + m * 16 + g * 4 + r;
      float s = 0.f, s2 = 0.f;
#pragma unroll
      for (int n = 0; n < 4; ++n) {
        const int col = wc * 64 + n * 16 + lc;
        float v = 0.f;
        if (col < 116)
          v = acc[m][n][r] + bias[col] + res[(size_t)row * 116 + col];
        acc[m][n][r] = v;
        s += v;
        s2 = fmaf(v, v, s2);
      }
#pragma unroll
      for (int st = 1; st < 16; st <<= 1) {
        s += __shfl_xor(s, st, 16);
        s2 += __shfl_xor(s2, st, 16);
      }
      s1l[m][r] = s;
      s2l[m][r] = s2;
    }
  }
  if (lc == 0) {
#pragma unroll
    for (int m = 0; m < 2; ++m)
#pragma unroll
      for (int r = 0; r < 4; ++r) {
        const int lrow = wr * 32 + m * 16 + g * 4 + r;
        sum1[wc][lrow] = s1l[m][r];
        sum2[wc][lrow] = s2l[m][r];
      }
  }
  __syncthreads();
#pragma unroll
  for (int m = 0; m < 2; ++m) {
#pragma unroll
    for (int r = 0; r < 4; ++r) {
      const int lrow = wr * 32 + m * 16 + g * 4 + r;
      const int row = M0 + lrow;
      const float st = sum1[0][lrow] + sum1[1][lrow];
      const float s2t = sum2[0][lrow] + sum2[1][lrow];
      const float mean = st * (1.f / 116.f);
      const float var = s2t * (1.f / 116.f) - mean * mean;
      const float rstd = 1.f / sqrtf(var + 1e-5f);
#pragma unroll
      for (int n = 0; n < 4; ++n) {
        const int col = wc * 64 + n * 16 + lc;
        if (col < 116) {
          const float y = (acc[m][n][r] - mean) * rstd * gw[col] + bw[col];
          Yf[(size_t)row * 116 + col] = y;
          Yb[(size_t)row * 128 + col] = f2bf(y);
        } else {
          Yb[(size_t)row * 128 + col] = 0;
        }
      }
    }
  }
}

// ---------------------------------------------------------------------------
// Fused FFN v2 (best measured): 512 threads / 8 waves, 128-token tile,
// DFF chunk 128, padded Hs, W register prefetch.
// ---------------------------------------------------------------------------
__global__ __launch_bounds__(512, 1) void ffn_fused2_kernel(
    const unsigned short* __restrict__ Xa,  // bf16 [32768][128]
    const unsigned short* __restrict__ W1,  // bf16 [2048][128]
    const float* __restrict__ b1,
    const unsigned short* __restrict__ W2,  // bf16 [116][2048]
    const float* __restrict__ b2, const float* __restrict__ res,
    const float* __restrict__ gw, const float* __restrict__ bw,
    unsigned short* __restrict__ Yb,  // bf16 [32768][128]
    float* __restrict__ Yf) {         // fp32 [32768][116]
  __shared__ __align__(16) unsigned short Xs[128][128];
  __shared__ __align__(16) unsigned short W1c[128][128];
  __shared__ __align__(16) unsigned short W2c[128][128];
  __shared__ __align__(16) unsigned short Hs[128][136];
  __shared__ float sum1[2][128];
  __shared__ float sum2[2][128];

  const int tid = threadIdx.x;
  const int M0 = blockIdx.x * 128;
  const int wid = tid >> 6, lane = tid & 63;
  const int wtr = wid >> 1, wdc = wid & 1;
  const int lc = lane & 15, g = lane >> 4;
  const int srow = tid >> 2, aq = tid & 3;

  {
    const uint4* p = reinterpret_cast<const uint4*>(
        Xa + (size_t)(M0 + srow) * 128 + aq * 32);
#pragma unroll
    for (int q = 0; q < 4; ++q) {
      const int cj = aq * 4 + q;
      const int swz = (cj & 8) | ((cj ^ srow) & 7);
      *reinterpret_cast<uint4*>(&Xs[srow][swz * 8]) = p[q];
    }
  }

  uint4 w1r[4], w2r[4];
  {
    const uint4* p1 =
        reinterpret_cast<const uint4*>(W1 + (size_t)srow * 128 + aq * 32);
#pragma unroll
    for (int q = 0; q < 4; ++q) w1r[q] = p1[q];
    uint4 z = {0, 0, 0, 0};
    w2r[0] = z; w2r[1] = z; w2r[2] = z; w2r[3] = z;
    if (srow < 116) {
      const uint4* p2 =
          reinterpret_cast<const uint4*>(W2 + (size_t)srow * 2048 + aq * 32);
#pragma unroll
      for (int q = 0; q < 4; ++q) w2r[q] = p2[q];
    }
  }

  floatx4 oacc[2][4] = {};

  for (int kc = 0; kc < 16; ++kc) {
#pragma unroll
    for (int q = 0; q < 4; ++q) {
      const int cj = aq * 4 + q;
      const int swz = (cj & 8) | ((cj ^ srow) & 7);
      *reinterpret_cast<uint4*>(&W1c[srow][swz * 8]) = w1r[q];
      *reinterpret_cast<uint4*>(&W2c[srow][swz * 8]) = w2r[q];
    }
    if (kc < 15) {
      const uint4* p1 = reinterpret_cast<const uint4*>(
          W1 + (size_t)((kc + 1) * 128 + srow) * 128 + aq * 32);
#pragma unroll
      for (int q = 0; q < 4; ++q) w1r[q] = p1[q];
      if (srow < 116) {
        const uint4* p2 = reinterpret_cast<const uint4*>(
            W2 + (size_t)srow * 2048 + (kc + 1) * 128 + aq * 32);
#pragma unroll
        for (int q = 0; q < 4; ++q) w2r[q] = p2[q];
      }
    }
    __syncthreads();

    floatx4 hacc[2][4] = {};
#pragma unroll
    for (int ks = 0; ks < 4; ++ks) {
      short8v av[2], bv[4];
      const int cj = ks * 4 + g;
#pragma unroll
      for (int m = 0; m < 2; ++m) {
        const int row = wtr * 32 + m * 16 + lc;
        const int swz = (cj & 8) | ((cj ^ row) & 7);
        av[m] = *reinterpret_cast<const short8v*>(&Xs[row][swz * 8]);
      }
#pragma unroll
      for (int n = 0; n < 4; ++n) {
        const int row = wdc * 64 + n * 16 + lc;
        const int swz = (cj & 8) | ((cj ^ row) & 7);
        bv[n] = *reinterpret_cast<const short8v*>(&W1c[row][swz * 8]);
      }
#pragma unroll
      for (int m = 0; m < 2; ++m)
#pragma unroll
        for (int n = 0; n < 4; ++n)
          hacc[m][n] = __builtin_amdgcn_mfma_f32_16x16x32_bf16(av[m], bv[n],
                                                               hacc[m][n], 0, 0, 0);
    }
#pragma unroll
    for (int n = 0; n < 4; ++n) {
      const int dff = wdc * 64 + n * 16 + lc;
      const float bb = b1[kc * 128 + dff];
#pragma unroll
      for (int m = 0; m < 2; ++m) {
#pragma unroll
        for (int r = 0; r < 4; ++r) {
          const int tok = wtr * 32 + m * 16 + g * 4 + r;
          Hs[tok][dff] = f2bf(fmaxf(hacc[m][n][r] + bb, 0.f));
        }
      }
    }
    __syncthreads();

#pragma unroll
    for (int ks = 0; ks < 4; ++ks) {
      short8v av[2], bv[4];
      const int cj = ks * 4 + g;
#pragma unroll
      for (int m = 0; m < 2; ++m) {
        const int row = wtr * 32 + m * 16 + lc;
        av[m] = *reinterpret_cast<const short8v*>(&Hs[row][cj * 8]);
      }
#pragma unroll
      for (int n = 0; n < 4; ++n) {
        const int col = wdc * 64 + n * 16 + lc;
        const int swz = (cj & 8) | ((cj ^ col) & 7);
        bv[n] = *reinterpret_cast<const short8v*>(&W2c[col][swz * 8]);
      }
#pragma unroll
      for (int m = 0; m < 2; ++m)
#pragma unroll
        for (int n = 0; n < 4; ++n)
          oacc[m][n] = __builtin_amdgcn_mfma_f32_16x16x32_bf16(av[m], bv[n],
                                                               oacc[m][n], 0, 0, 0);
    }
    __syncthreads();
  }

  float s1l[2][4], s2l[2][4];
#pragma unroll
  for (int m = 0; m < 2; ++m) {
#pragma unroll
    for (int r = 0; r < 4; ++r) {
      const int row = M0 + wtr * 32 + m * 16 + g * 4 + r;
      float s = 0.f, s2 = 0.f;
#pragma unroll
      for (int n = 0; n < 4; ++n) {
        const int col = wdc * 64 + n * 16 + lc;
        float v = 0.f;
        if (col < 116)
          v = oacc[m][n][r] + b2[col] + res[(size_t)row * 116 + col];
        oacc[m][n][r] = v;
        s += v;
        s2 = fmaf(v, v, s2);
      }
#pragma unroll
      for (int st = 1; st < 16; st <<= 1) {
        s += __shfl_xor(s, st, 16);
        s2 += __shfl_xor(s2, st, 16);
      }
      s1l[m][r] = s;
      s2l[m][r] = s2;
    }
  }
  if (lc == 0) {
#pragma unroll
    for (int m = 0; m < 2; ++m)
#pragma unroll
      for (int r = 0; r < 4; ++r) {
        const int lrow = wtr * 32 + m * 16 + g * 4 + r;
        sum1[wdc][lrow] = s1l[m][r];
        sum2[wdc][lrow] = s2l[m][r];
      }
  }
  __syncthreads();
#pragma unroll
  for (int m = 0; m < 2; ++m) {
#pragma unroll
    for (int r = 0; r < 4; ++r) {
      const int lrow = wtr * 32 + m * 16 + g * 4 + r;
      const int row = M0 + lrow;
      const float st = sum1[0][lrow] + sum1[1][lrow];
      const float s2t = sum2[0][lrow] + sum2[1][lrow];
      const float mean = st * (1.f / 116.f);
      const float var = s2t * (1.f / 116.f) - mean * mean;
      const float rstd = 1.f / sqrtf(var + 1e-5f);
#pragma unroll
      for (int n = 0; n < 4; ++n) {
        const int col = wdc * 64 + n * 16 + lc;
        if (col < 116) {
          const float y = (oacc[m][n][r] - mean) * rstd * gw[col] + bw[col];
          Yf[(size_t)row * 116 + col] = y;
          Yb[(size_t)row * 128 + col] = f2bf(y);
        } else {
          Yb[(size_t)row * 128 + col] = 0;
        }
      }
    }
  }
}

// ---------------------------------------------------------------------------
// Attention, head-major coalesced I/O.
// ---------------------------------------------------------------------------
__global__ __launch_bounds__(64) void attn_kernel(
    const unsigned short* __restrict__ qkvp, unsigned short* __restrict__ obuf) {
  const int h = blockIdx.x & 3;
  const int n = blockIdx.x >> 2;
  const int s = threadIdx.x;
  __shared__ float ks[64][36];
  __shared__ float vs[64][36];

  const size_t rb = (((size_t)n * 4 + h) * 64 + s) * 32;
  const uint4* qp = reinterpret_cast<const uint4*>(qkvp + rb);
  const uint4* kp = reinterpret_cast<const uint4*>(qkvp + 4194304 + rb);
  const uint4* vp = reinterpret_cast<const uint4*>(qkvp + 8388608 + rb);
  uint4 qv[4], kv4[4], vv4[4];
#pragma unroll
  for (int i = 0; i < 4; ++i) {
    qv[i] = qp[i];
    kv4[i] = kp[i];
    vv4[i] = vp[i];
  }
  float q[32], kf[32], vf[32];
#pragma unroll
  for (int i = 0; i < 4; ++i) {
    const unsigned* wq = reinterpret_cast<const unsigned*>(&qv[i]);
    const unsigned* wk = reinterpret_cast<const unsigned*>(&kv4[i]);
    const unsigned* wv = reinterpret_cast<const unsigned*>(&vv4[i]);
#pragma unroll
    for (int j = 0; j < 4; ++j) {
      union { unsigned u; float f; } lo, hi;
      const int d0 = i * 8 + 2 * j;
      lo.u = wq[j] << 16; hi.u = wq[j] & 0xffff0000u;
      q[d0] = lo.f; q[d0 + 1] = hi.f;
      lo.u = wk[j] << 16; hi.u = wk[j] & 0xffff0000u;
      kf[d0] = (d0 < 29) ? lo.f : 0.f;
      kf[d0 + 1] = (d0 + 1 < 29) ? hi.f : 0.f;
      lo.u = wv[j] << 16; hi.u = wv[j] & 0xffff0000u;
      vf[d0] = (d0 < 29) ? lo.f : 0.f;
      vf[d0 + 1] = (d0 + 1 < 29) ? hi.f : 0.f;
    }
  }
  q[29] = q[30] = q[31] = 0.f;
#pragma unroll
  for (int c = 0; c < 8; ++c) {
    *reinterpret_cast<float4*>(&ks[s][c * 4]) =
        make_float4(kf[4 * c], kf[4 * c + 1], kf[4 * c + 2], kf[4 * c + 3]);
    *reinterpret_cast<float4*>(&vs[s][c * 4]) =
        make_float4(vf[4 * c], vf[4 * c + 1], vf[4 * c + 2], vf[4 * c + 3]);
  }
  __syncthreads();

  const float scale = 0.18569533817705186f;  // 1/sqrt(29)
  float sc[64];
#pragma unroll 4
  for (int t = 0; t < 64; ++t) {
    const float4* kr = reinterpret_cast<const float4*>(&ks[t][0]);
    float a = 0.f;
#pragma unroll
    for (int c = 0; c < 8; ++c) {
      const float4 kc = kr[c];
      a = fmaf(q[4 * c], kc.x, a);
      a = fmaf(q[4 * c + 1], kc.y, a);
      a = fmaf(q[4 * c + 2], kc.z, a);
      a = fmaf(q[4 * c + 3], kc.w, a);
    }
    sc[t] = a * scale;
  }
  float m = sc[0];
#pragma unroll
  for (int t = 1; t < 64; ++t) m = fmaxf(m, sc[t]);
  float sum = 0.f;
#pragma unroll
  for (int t = 0; t < 64; ++t) {
    sc[t] = __expf(sc[t] - m);
    sum += sc[t];
  }
  const float inv = 1.f / sum;
  float o[32] = {};
#pragma unroll 4
  for (int t = 0; t < 64; ++t) {
    const float p = sc[t];
    const float4* vr = reinterpret_cast<const float4*>(&vs[t][0]);
#pragma unroll
    for (int c = 0; c < 8; ++c) {
      const float4 vc = vr[c];
      o[4 * c] = fmaf(p, vc.x, o[4 * c]);
      o[4 * c + 1] = fmaf(p, vc.y, o[4 * c + 1]);
      o[4 * c + 2] = fmaf(p, vc.z, o[4 * c + 2]);
      o[4 * c + 3] = fmaf(p, vc.w, o[4 * c + 3]);
    }
  }
  unsigned short ow[32];
#pragma unroll
  for (int i = 0; i < 32; ++i) ow[i] = f2bf(o[i] * inv);
  uint4* od =
      reinterpret_cast<uint4*>(obuf + ((size_t)s * 512 + n) * 128 + h * 32);
  const uint4* ows = reinterpret_cast<const uint4*>(ow);
#pragma unroll
  for (int i = 0; i < 4; ++i) od[i] = ows[i];
}

// ---------------------------------------------------------------------------
// fc fused with feaT/fn production.
// ---------------------------------------------------------------------------
__global__ __launch_bounds__(256) void fc_kernel(
    const float* __restrict__ X4, const float* __restrict__ fw,
    const float* __restrict__ fb, float* __restrict__ fea,
    unsigned short* __restrict__ feaT, float* __restrict__ fn) {
  const int eg = blockIdx.x;  // 0..3
  const int b = blockIdx.y;   // 0..63
  const int e0 = eg * 29;
  __shared__ float Os[64][30];
  __shared__ float Wf[64][65];
  const int tid = threadIdx.x;
  const int h = tid & 63, jg = tid >> 6;
  float acc[8] = {};

  for (int tc = 0; tc < 8; ++tc) {
    for (int idx = tid; idx < 64 * 29; idx += 256) {
      int tt = idx / 29;
      int ee = idx - tt * 29;
      Os[tt][ee] = X4[((size_t)b * 512 + tc * 64 + tt) * 116 + e0 + ee];
    }
    for (int idx = tid; idx < 64 * 64; idx += 256) {
      int hh = idx >> 6, t2 = idx & 63;
      Wf[hh][t2] = fw[(size_t)hh * 512 + tc * 64 + t2];
    }
    __syncthreads();
#pragma unroll 4
    for (int t = 0; t < 64; ++t) {
      const float w = Wf[h][t];
#pragma unroll
      for (int m = 0; m < 8; ++m) {
        const int el = jg + 4 * m;
        if (el < 29) acc[m] = fmaf(Os[t][el], w, acc[m]);
      }
    }
    __syncthreads();
  }
  const float bb = fb[h];
#pragma unroll
  for (int m = 0; m < 8; ++m) {
    const int el = jg + 4 * m;
    if (el < 29) {
      const float v = acc[m] + bb;
      const int e = e0 + el;
      fea[((size_t)b * 64 + h) * 116 + e] = v;
      if (feaT) {
        const unsigned short vb = f2bf(v);
        feaT[((size_t)b * 128 + e) * 64 + h] = vb;
        float s = bf2f(vb);
        s = s * s;
#pragma unroll
        for (int st = 1; st <= 32; st <<= 1) s += __shfl_xor(s, st, 64);
        if (h == 0) fn[b * 128 + e] = sqrtf(s);
      }
    }
  }
}

// ---------------------------------------------------------------------------
// simT prep: simT[a][c(96)][h(64)] bf16, sn[a][96].
// ---------------------------------------------------------------------------
__global__ __launch_bounds__(256) void simt_prep_kernel(
    const float* __restrict__ simin, unsigned short* __restrict__ simT,
    float* __restrict__ sn) {
  __shared__ float L[64][91];
  const int a = blockIdx.x;
  const int tid = threadIdx.x;
  for (int idx = tid; idx < 64 * 90; idx += 256) {
    const int h = idx / 90, c = idx - h * 90;
    L[h][c] = bf2f(f2bf(simin[((size_t)a * 64 + h) * 90 + c]));
  }
  __syncthreads();
  for (int idx = tid; idx < 96 * 64; idx += 256) {
    const int c = idx >> 6, h = idx & 63;
    simT[((size_t)a * 96 + c) * 64 + h] = (c < 90) ? f2bf(L[h][c]) : 0;
  }
  if (tid < 90) {
    float s = 0.f;
#pragma unroll 8
    for (int h = 0; h < 64; ++h) {
      const float t = L[h][tid];
      s = fmaf(t, t, s);
    }
    sn[a * 96 + tid] = sqrtf(s);
  }
}

// ---------------------------------------------------------------------------
// Similarity v5: 512 threads / 8 waves (4 d-quarters x 2 c-halves).
// Block = (b, 4 consecutive a's); same single-barrier structure as v3 but
// halved per-iteration non-store phase time (stage/MFMA/epilogue split 2x).
// ---------------------------------------------------------------------------
__global__ __launch_bounds__(512, 2) void sim_mfma5_kernel(
    const unsigned short* __restrict__ feaT, const unsigned short* __restrict__ simT,
    const float* __restrict__ fn, const float* __restrict__ sn,
    float* __restrict__ simil, float* __restrict__ similar) {
  const int a0 = blockIdx.x * 4;  // 0,4,...,112
  const int b = blockIdx.y;       // 0..63
  __shared__ __align__(16) unsigned short Ft[128][64];
  __shared__ __align__(16) unsigned short St[96][64];
  __shared__ __align__(16) float Rs[10440];
  __shared__ float fnrow[116];
  __shared__ float snrow[90];
  __shared__ float wred[8];
  const int tid = threadIdx.x;
  const int srow = tid >> 2, q4 = tid & 3;   // staging: 4 thr/row, 2 uint4 ea
  const int wid = tid >> 6, lane = tid & 63;
  const int wr = wid >> 1;                   // 0..3: d-quarter (32 rows)
  const int wc = wid & 1;                    // 0..1: c-half (48 cols)
  const int lc = lane & 15, g = lane >> 4;

  // stage Ft + fnrow once (swz chunk = cj ^ (row&7), cj = q4*2+q in 0..7)
  {
    const int sw = srow & 7;
    const uint4* p = reinterpret_cast<const uint4*>(
        feaT + ((size_t)b * 128 + srow) * 64 + q4 * 16);
    uint4 v0 = p[0], v1 = p[1];
    *reinterpret_cast<uint4*>(&Ft[srow][(((q4 * 2) ^ sw) << 3)]) = v0;
    *reinterpret_cast<uint4*>(&Ft[srow][(((q4 * 2 + 1) ^ sw) << 3)]) = v1;
  }
  if (tid < 116) fnrow[tid] = fn[b * 128 + tid];

  for (int ai = 0; ai < 4; ++ai) {
    const int a = a0 + ai;
    if (srow < 96) {
      const int sw = srow & 7;
      const uint4* p = reinterpret_cast<const uint4*>(
          simT + ((size_t)a * 96 + srow) * 64 + q4 * 16);
      uint4 v0 = p[0], v1 = p[1];
      *reinterpret_cast<uint4*>(&St[srow][(((q4 * 2) ^ sw) << 3)]) = v0;
      *reinterpret_cast<uint4*>(&St[srow][(((q4 * 2 + 1) ^ sw) << 3)]) = v1;
    }
    if (tid >= 416 && tid < 506) snrow[tid - 416] = sn[a * 96 + (tid - 416)];
    __syncthreads();

    floatx4 acc[2][3] = {};
#pragma unroll
    for (int ks = 0; ks < 2; ++ks) {
      short8v av[2], bv[3];
#pragma unroll
      for (int m = 0; m < 2; ++m) {
        const int row = wr * 32 + m * 16 + lc;
        av[m] = *reinterpret_cast<const short8v*>(
            &Ft[row][((((ks << 2) | g) ^ (lc & 7)) << 3)]);
      }
#pragma unroll
      for (int n = 0; n < 3; ++n) {
        const int col = wc * 48 + n * 16 + lc;
        bv[n] = *reinterpret_cast<const short8v*>(
            &St[col][((((ks << 2) | g) ^ (lc & 7)) << 3)]);
      }
#pragma unroll
      for (int m = 0; m < 2; ++m)
#pragma unroll
        for (int n = 0; n < 3; ++n)
          acc[m][n] = __builtin_amdgcn_mfma_f32_16x16x32_bf16(av[m], bv[n],
                                                              acc[m][n], 0, 0, 0);
    }

    float ss = 0.f;
#pragma unroll
    for (int m = 0; m < 2; ++m) {
#pragma unroll
      for (int r = 0; r < 4; ++r) {
        const int d = wr * 32 + m * 16 + g * 4 + r;
        if (d < 116) {
          const float fnv = fnrow[d];
#pragma unroll
          for (int n = 0; n < 3; ++n) {
            const int c = wc * 48 + n * 16 + lc;
            if (c < 90) {
              const float denom = fmaxf(fnv * snrow[c], 1e-8f);
              float rcp = __builtin_amdgcn_rcpf(denom);
              rcp = rcp * (2.0f - denom * rcp);
              const float v = acc[m][n][r] * rcp;
              ss = fmaf(v, v, ss);
              Rs[d * 90 + c] = v;
            }
          }
        }
      }
    }
#pragma unroll
    for (int st = 1; st <= 32; st <<= 1) ss += __shfl_xor(ss, st, 64);
    if (lane == 0) wred[wid] = ss;
    __syncthreads();
    const float tot = wred[0] + wred[1] + wred[2] + wred[3] + wred[4] +
                      wred[5] + wred[6] + wred[7];
    const float inv = 1.f / fmaxf(sqrtf(tot), 1e-12f);

    const size_t rowbase = ((size_t)b * 116 + a) * (116 * 90);
    float4* so = reinterpret_cast<float4*>(simil + rowbase);
    float4* sr = reinterpret_cast<float4*>(similar + rowbase);
    const float4* rs4 = reinterpret_cast<const float4*>(Rs);
    for (int i = tid; i < 2610; i += 512) {
      float4 v = rs4[i];
      so[i] = v;
      float4 w;
      w.x = v.x * inv; w.y = v.y * inv; w.z = v.z * inv; w.w = v.w * inv;
      sr[i] = w;
    }
  }
}

// ---------------------------------------------------------------------------
// Fallback similarity (self-contained) if d_ws is too small.
// ---------------------------------------------------------------------------
__global__ __launch_bounds__(256) void sim_mfma_kernel(
    const float* __restrict__ fea, const float* __restrict__ simin,
    float* __restrict__ simil, float* __restrict__ similar) {
  const int a = blockIdx.x;
  const int b = blockIdx.y;
  __shared__ __align__(16) unsigned char shmem[41760];
  __shared__ float fnrow[116];
  __shared__ float snrow[90];
  __shared__ float wred[4];
  const int tid = threadIdx.x;

  unsigned short (*Ft)[64] = reinterpret_cast<unsigned short(*)[64]>(shmem);
  unsigned short (*St)[64] =
      reinterpret_cast<unsigned short(*)[64]>(shmem + 16384);
  float* Rs = reinterpret_cast<float*>(shmem);

  for (int idx = tid; idx < 64 * 116; idx += 256) {
    const int h = idx / 116, d = idx - h * 116;
    Ft[d][(((h >> 3) ^ (d & 7)) << 3) | (h & 7)] =
        f2bf(fea[((size_t)b * 64 + h) * 116 + d]);
  }
  for (int idx = tid; idx < 12 * 64; idx += 256) {
    const int d = 116 + (idx >> 6), h = idx & 63;
    Ft[d][(((h >> 3) ^ (d & 7)) << 3) | (h & 7)] = 0;
  }
  for (int idx = tid; idx < 64 * 90; idx += 256) {
    const int h = idx / 90, c = idx - h * 90;
    St[c][(((h >> 3) ^ (c & 7)) << 3) | (h & 7)] =
        f2bf(simin[((size_t)a * 64 + h) * 90 + c]);
  }
  for (int idx = tid; idx < 6 * 64; idx += 256) {
    const int c = 90 + (idx >> 6), h = idx & 63;
    St[c][(((h >> 3) ^ (c & 7)) << 3) | (h & 7)] = 0;
  }
  __syncthreads();

  if (tid < 116) {
    float s = 0.f;
#pragma unroll 8
    for (int h = 0; h < 64; ++h) {
      const float t = bf2f(Ft[tid][(((h >> 3) ^ (tid & 7)) << 3) | (h & 7)]);
      s = fmaf(t, t, s);
    }
    fnrow[tid] = sqrtf(s);
  } else if (tid >= 128 && tid < 218) {
    const int c = tid - 128;
    float s = 0.f;
#pragma unroll 8
    for (int h = 0; h < 64; ++h) {
      const float t = bf2f(St[c][(((h >> 3) ^ (c & 7)) << 3) | (h & 7)]);
      s = fmaf(t, t, s);
    }
    snrow[c] = sqrtf(s);
  }
  __syncthreads();

  const int wid = tid >> 6, lane = tid & 63;
  const int wr = wid >> 1, wc = wid & 1;
  const int lc = lane & 15, g = lane >> 4;

  floatx4 acc[4][3] = {};
#pragma unroll
  for (int ks = 0; ks < 2; ++ks) {
    short8v av[4], bv[3];
#pragma unroll
    for (int m = 0; m < 4; ++m) {
      const int row = wr * 64 + m * 16 + lc;
      av[m] = *reinterpret_cast<const short8v*>(
          &Ft[row][((((ks << 2) | g) ^ (lc & 7)) << 3)]);
    }
#pragma unroll
    for (int n = 0; n < 3; ++n) {
      const int col = wc * 48 + n * 16 + lc;
      bv[n] = *reinterpret_cast<const short8v*>(
          &St[col][((((ks << 2) | g) ^ (lc & 7)) << 3)]);
    }
#pragma unroll
    for (int m = 0; m < 4; ++m)
#pragma unroll
      for (int n = 0; n < 3; ++n)
        acc[m][n] = __builtin_amdgcn_mfma_f32_16x16x32_bf16(av[m], bv[n],
                                                            acc[m][n], 0, 0, 0);
  }
  __syncthreads();

  float ss = 0.f;
#pragma unroll
  for (int m = 0; m < 4; ++m) {
#pragma unroll
    for (int r = 0; r < 4; ++r) {
      const int d = wr * 64 + m * 16 + g * 4 + r;
      if (d < 116) {
        const float fnv = fnrow[d];
#pragma unroll
        for (int n = 0; n < 3; ++n) {
          const int c = wc * 48 + n * 16 + lc;
          if (c < 90) {
            const float denom = fmaxf(fnv * snrow[c], 1e-8f);
            float rcp = __builtin_amdgcn_rcpf(denom);
            rcp = rcp * (2.0f - denom * rcp);
            const float v = acc[m][n][r] * rcp;
            ss = fmaf(v, v, ss);
            Rs[d * 90 + c] = v;
          }
        }
      }
    }
  }
#pragma unroll
  for (int st = 1; st <= 32; st <<= 1) ss += __shfl_xor(ss, st, 64);
  if (lane == 0) wred[wid] = ss;
  __syncthreads();
  const float tot = wred[0] + wred[1] + wred[2] + wred[3];
  const float inv = 1.f / fmaxf(sqrtf(tot), 1e-12f);

  const size_t rowbase = ((size_t)b * 116 + a) * (116 * 90);
  float4* so = reinterpret_cast<float4*>(simil + rowbase);
  float4* sr = reinterpret_cast<float4*>(similar + rowbase);
  const float4* rs4 = reinterpret_cast<const float4*>(Rs);
  for (int i = tid; i < 2610; i += 256) {
    float4 v = rs4[i];
    so[i] = v;
    float4 w;
    w.x = v.x * inv; w.y = v.y * inv; w.z = v.z * inv; w.w = v.w * inv;
    sr[i] = w;
  }
}

// ---------------------------------------------------------------------------
extern "C" void kernel_launch(void* const* d_in, const int* in_sizes, int n_in,
                              void* d_out, int out_size, void* d_ws,
                              size_t ws_size, hipStream_t stream) {
  const float* x0 = (const float*)d_in[0];
  const float* simin = (const float*)d_in[1];
  const float* p[24];
  for (int i = 0; i < 24; ++i) p[i] = (const float*)d_in[2 + i];
  const float* fc_w = (const float*)d_in[26];
  const float* fc_b = (const float*)d_in[27];

  float* out = (float*)d_out;
  float* fea = out;
  float* simil = out + 475136;       // 77,506,560 floats
  float* similar = out + 77981696;   // 475136 + 77506560

  // scratch in 'similar' region (all dead before sim writes it):
  float* xa_f[2] = {similar + 0, similar + 7602176};
  float* xb_f[2] = {similar + 3801088, similar + 11403264};
  unsigned short* obufb = (unsigned short*)(similar + 15204352);
  unsigned short* qkvp = (unsigned short*)(similar + 17301504);
  unsigned short* Ab = (unsigned short*)(similar + 23592960);
  unsigned short* xab[2] = {(unsigned short*)(similar + 25690112),
                            (unsigned short*)(similar + 29884416)};
  unsigned short* xbb[2] = {(unsigned short*)(similar + 27787264),
                            (unsigned short*)(similar + 31981568)};
  // scratch in 'simil' region:
  unsigned short* wbuf = (unsigned short*)(simil + 33554432);
  const size_t WSZ = 559104;

  // d_ws layout for sim (bytes)
  unsigned char* ws = (unsigned char*)d_ws;
  unsigned short* feaT = (unsigned short*)ws;                   // 1,048,576 B
  unsigned short* simT = (unsigned short*)(ws + 1048576);       // 1,425,408 B
  float* fnb = (float*)(ws + 2473984);
  float* snb = (float*)(ws + 2506752);
  const bool ws_ok = ws_size >= 2551296;

  {
    ConvJobs J;
    int cum = 0;
    auto add = [&](int j, const float* s, unsigned short* dd, int R, int K,
                   int Kp, int mode) {
      J.src[j] = s; J.dst[j] = dd; J.K[j] = K; J.Kp[j] = Kp; J.mode[j] = mode;
      J.cum[j] = cum; cum += R * Kp;
    };
    add(0, x0, Ab, 32768, 116, 128, 0);
    for (int L = 0; L < 2; ++L) {
      unsigned short* wb = wbuf + L * WSZ;
      add(1 + L * 4, p[L * 12 + 0], wb + 0, 348, 116, 128, 0);
      add(2 + L * 4, p[L * 12 + 2], wb + 44544, 116, 116, 128, 1);
      add(3 + L * 4, p[L * 12 + 6], wb + 59392, 2048, 116, 128, 0);
      add(4 + L * 4, p[L * 12 + 8], wb + 321536, 116, 2048, 2048, 0);
    }
    J.cum[9] = cum;
    hipLaunchKernelGGL(convert_all_kernel, dim3(2048), dim3(256), 0, stream, J);
  }

  if (ws_ok) {
    hipLaunchKernelGGL(simt_prep_kernel, dim3(116), dim3(256), 0, stream,
                       simin, simT, snb);
  }

  const unsigned short* Ain = Ab;
  const float* resin = x0;
  for (int L = 0; L < 2; ++L) {
    unsigned short* wb = wbuf + L * WSZ;
    const float* bqkv = p[L * 12 + 1];
    const float* bo = p[L * 12 + 3];
    const float* g1 = p[L * 12 + 4];
    const float* bn1 = p[L * 12 + 5];
    const float* b1 = p[L * 12 + 7];
    const float* b2 = p[L * 12 + 9];
    const float* g2 = p[L * 12 + 10];
    const float* bn2 = p[L * 12 + 11];

    hipLaunchKernelGGL(qkv_gemm_kernel, dim3(256, 3), dim3(256), 0, stream,
                       Ain, wb + 0, bqkv, qkvp);
    hipLaunchKernelGGL(attn_kernel, dim3(2048), dim3(64), 0, stream, qkvp,
                       obufb);
    hipLaunchKernelGGL(mgemm64_ln_kernel, dim3(512), dim3(256), 0, stream,
                       obufb, wb + 44544, bo, 128, xab[L], xa_f[L], resin, g1,
                       bn1);
    hipLaunchKernelGGL(ffn_fused2_kernel, dim3(256), dim3(512), 0, stream,
                       xab[L], wb + 59392, b1, wb + 321536, b2, xa_f[L], g2,
                       bn2, xbb[L], xb_f[L]);
    Ain = xbb[L];
    resin = xb_f[L];
  }

  if (ws_ok) {
    hipLaunchKernelGGL(fc_kernel, dim3(4, 64), dim3(256), 0, stream, xb_f[1],
                       fc_w, fc_b, fea, feaT, fnb);
    hipLaunchKernelGGL(sim_mfma5_kernel, dim3(29, 64), dim3(512), 0, stream,
                       feaT, simT, fnb, snb, simil, similar);
  } else {
    hipLaunchKernelGGL(fc_kernel, dim3(4, 64), dim3(256), 0, stream, xb_f[1],
                       fc_w, fc_b, fea, (unsigned short*)nullptr,
                       (float*)nullptr);
    hipLaunchKernelGGL(sim_mfma_kernel, dim3(116, 64), dim3(256), 0, stream,
                       fea, simin, simil, similar);
  }
}

// Round 16
// 605.983 us; speedup vs baseline: 1.1626x; 1.0049x over previous
//
#include <hip/hip_runtime.h>
#include <hip/hip_bf16.h>

typedef __attribute__((ext_vector_type(8))) short short8v;
typedef __attribute__((ext_vector_type(4))) float floatx4;

__device__ __forceinline__ float bf2f(unsigned short u) {
  union { unsigned int i; float f; } c;
  c.i = ((unsigned int)u) << 16;
  return c.f;
}
__device__ __forceinline__ unsigned short f2bf(float f) {
  __hip_bfloat16 h = __float2bfloat16(f);
  return *reinterpret_cast<unsigned short*>(&h);
}

// ---------------------------------------------------------------------------
// Fused conversion: 9 jobs fp32 -> bf16.
// ---------------------------------------------------------------------------
struct ConvJobs {
  const float* src[9];
  unsigned short* dst[9];
  int K[9];
  int Kp[9];
  int mode[9];
  int cum[10];
};

__global__ __launch_bounds__(256) void convert_all_kernel(ConvJobs J) {
  const int total = J.cum[9];
  for (int idx = blockIdx.x * 256 + threadIdx.x; idx < total;
       idx += gridDim.x * 256) {
    int j = 0;
    while (idx >= J.cum[j + 1]) ++j;
    const int local = idx - J.cum[j];
    const int Kp = J.Kp[j];
    const int r = local / Kp, c = local - r * Kp;
    unsigned short v;
    if (J.mode[j] == 0) {
      v = (c < J.K[j]) ? f2bf(J.src[j][(size_t)r * J.K[j] + c])
                       : (unsigned short)0;
    } else {
      const int h = c >> 5, d = c & 31;
      v = (d < 29) ? f2bf(J.src[j][(size_t)r * 116 + h * 29 + d])
                   : (unsigned short)0;
    }
    J.dst[j][local] = v;
  }
}

// ---------------------------------------------------------------------------
// qkv GEMM: grid (M/128, 3).  Coalesced head-major epilogue via LDS restage.
// Output qkvp[which][(n*4+h)*64+s][32] bf16.
// ---------------------------------------------------------------------------
__global__ __launch_bounds__(256) void qkv_gemm_kernel(
    const unsigned short* __restrict__ A,  // bf16 [32768][128]
    const unsigned short* __restrict__ B,  // bf16 [348][128] (wqkv)
    const float* __restrict__ bias,        // [348]
    unsigned short* __restrict__ qkvp) {
  __shared__ __align__(16) unsigned char shmem[32768];
  unsigned short (*As)[64] = reinterpret_cast<unsigned short(*)[64]>(shmem);
  unsigned short (*Bs)[64] =
      reinterpret_cast<unsigned short(*)[64]>(shmem + 16384);
  unsigned short (*Qt)[120] = reinterpret_cast<unsigned short(*)[120]>(shmem);

  const int tid = threadIdx.x;
  const int M0 = blockIdx.x * 128;
  const int which = blockIdx.y;  // 0..2
  const int wid = tid >> 6, lane = tid & 63;
  const int wr = wid >> 1, wc = wid & 1;
  const int lc = lane & 15, g = lane >> 4;
  const int srow = tid >> 1, shalf = tid & 1;
  const int sw = srow & 7;

  floatx4 acc[4][4] = {};

  for (int kt = 0; kt < 2; ++kt) {
    const int k0 = kt << 6;
    {
      const uint4* p = reinterpret_cast<const uint4*>(
          A + (size_t)(M0 + srow) * 128 + k0 + shalf * 32);
      uint4 v0 = p[0], v1 = p[1], v2 = p[2], v3 = p[3];
      *reinterpret_cast<uint4*>(&As[srow][((((shalf << 2) | 0) ^ sw) << 3)]) = v0;
      *reinterpret_cast<uint4*>(&As[srow][((((shalf << 2) | 1) ^ sw) << 3)]) = v1;
      *reinterpret_cast<uint4*>(&As[srow][((((shalf << 2) | 2) ^ sw) << 3)]) = v2;
      *reinterpret_cast<uint4*>(&As[srow][((((shalf << 2) | 3) ^ sw) << 3)]) = v3;
    }
    {
      uint4 v0 = {0, 0, 0, 0}, v1 = v0, v2 = v0, v3 = v0;
      if (srow < 116) {
        const uint4* p = reinterpret_cast<const uint4*>(
            B + (size_t)(which * 116 + srow) * 128 + k0 + shalf * 32);
        v0 = p[0]; v1 = p[1]; v2 = p[2]; v3 = p[3];
      }
      *reinterpret_cast<uint4*>(&Bs[srow][((((shalf << 2) | 0) ^ sw) << 3)]) = v0;
      *reinterpret_cast<uint4*>(&Bs[srow][((((shalf << 2) | 1) ^ sw) << 3)]) = v1;
      *reinterpret_cast<uint4*>(&Bs[srow][((((shalf << 2) | 2) ^ sw) << 3)]) = v2;
      *reinterpret_cast<uint4*>(&Bs[srow][((((shalf << 2) | 3) ^ sw) << 3)]) = v3;
    }
    __syncthreads();
#pragma unroll
    for (int ks = 0; ks < 2; ++ks) {
      short8v a[4], b[4];
#pragma unroll
      for (int m = 0; m < 4; ++m) {
        const int row = wr * 64 + m * 16 + lc;
        a[m] = *reinterpret_cast<const short8v*>(
            &As[row][((((ks << 2) | g) ^ (lc & 7)) << 3)]);
      }
#pragma unroll
      for (int n = 0; n < 4; ++n) {
        const int col = wc * 64 + n * 16 + lc;
        b[n] = *reinterpret_cast<const short8v*>(
            &Bs[col][((((ks << 2) | g) ^ (lc & 7)) << 3)]);
      }
#pragma unroll
      for (int m = 0; m < 4; ++m)
#pragma unroll
        for (int n = 0; n < 4; ++n)
          acc[m][n] = __builtin_amdgcn_mfma_f32_16x16x32_bf16(a[m], b[n],
                                                              acc[m][n], 0, 0, 0);
    }
    __syncthreads();
  }

#pragma unroll
  for (int m = 0; m < 4; ++m) {
#pragma unroll
    for (int r = 0; r < 4; ++r) {
      const int lrow = wr * 64 + m * 16 + g * 4 + r;
#pragma unroll
      for (int n = 0; n < 4; ++n) {
        const int col = wc * 64 + n * 16 + lc;
        if (col < 116)
          Qt[lrow][col] = f2bf(acc[m][n][r] + bias[which * 116 + col]);
      }
    }
  }
  __syncthreads();

  const int s_idx = M0 >> 9;
  const int nbase = M0 & 511;
  for (int idx = tid; idx < 2048; idx += 256) {
    const int dg = idx & 3, h = (idx >> 2) & 3, n = idx >> 4;
    unsigned short ow[8];
#pragma unroll
    for (int j = 0; j < 8; ++j) {
      const int d = dg * 8 + j;
      ow[j] = (d < 29) ? Qt[n][h * 29 + d] : (unsigned short)0;
    }
    uint4* dst = reinterpret_cast<uint4*>(
        qkvp + (size_t)which * 4194304 +
        ((((size_t)(nbase + n) * 4 + h) * 64 + s_idx) << 5) + dg * 8);
    *dst = *reinterpret_cast<const uint4*>(ow);
  }
}

// ---------------------------------------------------------------------------
// 64-row-tile GEMM + residual + LayerNorm (N=116).  Used for o-proj (K=128).
// ---------------------------------------------------------------------------
__global__ __launch_bounds__(256) void mgemm64_ln_kernel(
    const unsigned short* __restrict__ A, const unsigned short* __restrict__ B,
    const float* __restrict__ bias, int Kp, unsigned short* __restrict__ Yb,
    float* __restrict__ Yf, const float* __restrict__ res,
    const float* __restrict__ gw, const float* __restrict__ bw) {
  __shared__ __align__(16) unsigned short As[64][64];
  __shared__ __align__(16) unsigned short Bs[128][64];
  __shared__ float sum1[2][64];
  __shared__ float sum2[2][64];

  const int tid = threadIdx.x;
  const int M0 = blockIdx.x * 64;
  const int wid = tid >> 6, lane = tid & 63;
  const int wr = wid >> 1, wc = wid & 1;
  const int lc = lane & 15, g = lane >> 4;
  const int arow = tid >> 2, aq = tid & 3;
  const int brow = tid >> 1, bhalf = tid & 1;

  floatx4 acc[2][4] = {};

  const int nk = Kp >> 6;
  for (int kt = 0; kt < nk; ++kt) {
    const int k0 = kt << 6;
    {
      const uint4* p = reinterpret_cast<const uint4*>(
          A + (size_t)(M0 + arow) * Kp + k0 + aq * 16);
      uint4 v0 = p[0], v1 = p[1];
      const int swa = arow & 7;
      *reinterpret_cast<uint4*>(&As[arow][(((aq * 2) ^ swa) << 3)]) = v0;
      *reinterpret_cast<uint4*>(&As[arow][(((aq * 2 + 1) ^ swa) << 3)]) = v1;
    }
    {
      uint4 v0 = {0, 0, 0, 0}, v1 = v0, v2 = v0, v3 = v0;
      if (brow < 116) {
        const uint4* p = reinterpret_cast<const uint4*>(
            B + (size_t)brow * Kp + k0 + bhalf * 32);
        v0 = p[0]; v1 = p[1]; v2 = p[2]; v3 = p[3];
      }
      const int sw = brow & 7;
      *reinterpret_cast<uint4*>(&Bs[brow][((((bhalf << 2) | 0) ^ sw) << 3)]) = v0;
      *reinterpret_cast<uint4*>(&Bs[brow][((((bhalf << 2) | 1) ^ sw) << 3)]) = v1;
      *reinterpret_cast<uint4*>(&Bs[brow][((((bhalf << 2) | 2) ^ sw) << 3)]) = v2;
      *reinterpret_cast<uint4*>(&Bs[brow][((((bhalf << 2) | 3) ^ sw) << 3)]) = v3;
    }
    __syncthreads();
#pragma unroll
    for (int ks = 0; ks < 2; ++ks) {
      short8v a[2], b[4];
#pragma unroll
      for (int m = 0; m < 2; ++m) {
        const int row = wr * 32 + m * 16 + lc;
        a[m] = *reinterpret_cast<const short8v*>(
            &As[row][((((ks << 2) | g) ^ (row & 7)) << 3)]);
      }
#pragma unroll
      for (int n = 0; n < 4; ++n) {
        const int col = wc * 64 + n * 16 + lc;
        b[n] = *reinterpret_cast<const short8v*>(
            &Bs[col][((((ks << 2) | g) ^ (col & 7)) << 3)]);
      }
#pragma unroll
      for (int m = 0; m < 2; ++m)
#pragma unroll
        for (int n = 0; n < 4; ++n)
          acc[m][n] = __builtin_amdgcn_mfma_f32_16x16x32_bf16(a[m], b[n],
                                                              acc[m][n], 0, 0, 0);
    }
    __syncthreads();
  }

  float s1l[2][4], s2l[2][4];
#pragma unroll
  for (int m = 0; m < 2; ++m) {
#pragma unroll
    for (int r = 0; r < 4; ++r) {
      const int row = M0 + wr * 32 + m * 16 + g * 4 + r;
      float s = 0.f, s2 = 0.f;
#pragma unroll
      for (int n = 0; n < 4; ++n) {
        const int col = wc * 64 + n * 16 + lc;
        float v = 0.f;
        if (col < 116)
          v = acc[m][n][r] + bias[col] + res[(size_t)row * 116 + col];
        acc[m][n][r] = v;
        s += v;
        s2 = fmaf(v, v, s2);
      }
#pragma unroll
      for (int st = 1; st < 16; st <<= 1) {
        s += __shfl_xor(s, st, 16);
        s2 += __shfl_xor(s2, st, 16);
      }
      s1l[m][r] = s;
      s2l[m][r] = s2;
    }
  }
  if (lc == 0) {
#pragma unroll
    for (int m = 0; m < 2; ++m)
#pragma unroll
      for (int r = 0; r < 4; ++r) {
        const int lrow = wr * 32 + m * 16 + g * 4 + r;
        sum1[wc][lrow] = s1l[m][r];
        sum2[wc][lrow] = s2l[m][r];
      }
  }
  __syncthreads();
#pragma unroll
  for (int m = 0; m < 2; ++m) {
#pragma unroll
    for (int r = 0; r < 4; ++r) {
      const int lrow = wr * 32 + m * 16 + g * 4 + r;
      const int row = M0 + lrow;
      const float st = sum1[0][lrow] + sum1[1][lrow];
      const float s2t = sum2[0][lrow] + sum2[1][lrow];
      const float mean = st * (1.f / 116.f);
      const float var = s2t * (1.f / 116.f) - mean * mean;
      const float rstd = 1.f / sqrtf(var + 1e-5f);
#pragma unroll
      for (int n = 0; n < 4; ++n) {
        const int col = wc * 64 + n * 16 + lc;
        if (col < 116) {
          const float y = (acc[m][n][r] - mean) * rstd * gw[col] + bw[col];
          Yf[(size_t)row * 116 + col] = y;
          Yb[(size_t)row * 128 + col] = f2bf(y);
        } else {
          Yb[(size_t)row * 128 + col] = 0;
        }
      }
    }
  }
}

// ---------------------------------------------------------------------------
// Fused FFN v2 (best measured): 512 threads / 8 waves, 128-token tile,
// DFF chunk 128, padded Hs, W register prefetch.
// ---------------------------------------------------------------------------
__global__ __launch_bounds__(512, 1) void ffn_fused2_kernel(
    const unsigned short* __restrict__ Xa,  // bf16 [32768][128]
    const unsigned short* __restrict__ W1,  // bf16 [2048][128]
    const float* __restrict__ b1,
    const unsigned short* __restrict__ W2,  // bf16 [116][2048]
    const float* __restrict__ b2, const float* __restrict__ res,
    const float* __restrict__ gw, const float* __restrict__ bw,
    unsigned short* __restrict__ Yb,  // bf16 [32768][128]
    float* __restrict__ Yf) {         // fp32 [32768][116]
  __shared__ __align__(16) unsigned short Xs[128][128];
  __shared__ __align__(16) unsigned short W1c[128][128];
  __shared__ __align__(16) unsigned short W2c[128][128];
  __shared__ __align__(16) unsigned short Hs[128][136];
  __shared__ float sum1[2][128];
  __shared__ float sum2[2][128];

  const int tid = threadIdx.x;
  const int M0 = blockIdx.x * 128;
  const int wid = tid >> 6, lane = tid & 63;
  const int wtr = wid >> 1, wdc = wid & 1;
  const int lc = lane & 15, g = lane >> 4;
  const int srow = tid >> 2, aq = tid & 3;

  {
    const uint4* p = reinterpret_cast<const uint4*>(
        Xa + (size_t)(M0 + srow) * 128 + aq * 32);
#pragma unroll
    for (int q = 0; q < 4; ++q) {
      const int cj = aq * 4 + q;
      const int swz = (cj & 8) | ((cj ^ srow) & 7);
      *reinterpret_cast<uint4*>(&Xs[srow][swz * 8]) = p[q];
    }
  }

  uint4 w1r[4], w2r[4];
  {
    const uint4* p1 =
        reinterpret_cast<const uint4*>(W1 + (size_t)srow * 128 + aq * 32);
#pragma unroll
    for (int q = 0; q < 4; ++q) w1r[q] = p1[q];
    uint4 z = {0, 0, 0, 0};
    w2r[0] = z; w2r[1] = z; w2r[2] = z; w2r[3] = z;
    if (srow < 116) {
      const uint4* p2 =
          reinterpret_cast<const uint4*>(W2 + (size_t)srow * 2048 + aq * 32);
#pragma unroll
      for (int q = 0; q < 4; ++q) w2r[q] = p2[q];
    }
  }

  floatx4 oacc[2][4] = {};

  for (int kc = 0; kc < 16; ++kc) {
#pragma unroll
    for (int q = 0; q < 4; ++q) {
      const int cj = aq * 4 + q;
      const int swz = (cj & 8) | ((cj ^ srow) & 7);
      *reinterpret_cast<uint4*>(&W1c[srow][swz * 8]) = w1r[q];
      *reinterpret_cast<uint4*>(&W2c[srow][swz * 8]) = w2r[q];
    }
    if (kc < 15) {
      const uint4* p1 = reinterpret_cast<const uint4*>(
          W1 + (size_t)((kc + 1) * 128 + srow) * 128 + aq * 32);
#pragma unroll
      for (int q = 0; q < 4; ++q) w1r[q] = p1[q];
      if (srow < 116) {
        const uint4* p2 = reinterpret_cast<const uint4*>(
            W2 + (size_t)srow * 2048 + (kc + 1) * 128 + aq * 32);
#pragma unroll
        for (int q = 0; q < 4; ++q) w2r[q] = p2[q];
      }
    }
    __syncthreads();

    floatx4 hacc[2][4] = {};
#pragma unroll
    for (int ks = 0; ks < 4; ++ks) {
      short8v av[2], bv[4];
      const int cj = ks * 4 + g;
#pragma unroll
      for (int m = 0; m < 2; ++m) {
        const int row = wtr * 32 + m * 16 + lc;
        const int swz = (cj & 8) | ((cj ^ row) & 7);
        av[m] = *reinterpret_cast<const short8v*>(&Xs[row][swz * 8]);
      }
#pragma unroll
      for (int n = 0; n < 4; ++n) {
        const int row = wdc * 64 + n * 16 + lc;
        const int swz = (cj & 8) | ((cj ^ row) & 7);
        bv[n] = *reinterpret_cast<const short8v*>(&W1c[row][swz * 8]);
      }
#pragma unroll
      for (int m = 0; m < 2; ++m)
#pragma unroll
        for (int n = 0; n < 4; ++n)
          hacc[m][n] = __builtin_amdgcn_mfma_f32_16x16x32_bf16(av[m], bv[n],
                                                               hacc[m][n], 0, 0, 0);
    }
#pragma unroll
    for (int n = 0; n < 4; ++n) {
      const int dff = wdc * 64 + n * 16 + lc;
      const float bb = b1[kc * 128 + dff];
#pragma unroll
      for (int m = 0; m < 2; ++m) {
#pragma unroll
        for (int r = 0; r < 4; ++r) {
          const int tok = wtr * 32 + m * 16 + g * 4 + r;
          Hs[tok][dff] = f2bf(fmaxf(hacc[m][n][r] + bb, 0.f));
        }
      }
    }
    __syncthreads();

#pragma unroll
    for (int ks = 0; ks < 4; ++ks) {
      short8v av[2], bv[4];
      const int cj = ks * 4 + g;
#pragma unroll
      for (int m = 0; m < 2; ++m) {
        const int row = wtr * 32 + m * 16 + lc;
        av[m] = *reinterpret_cast<const short8v*>(&Hs[row][cj * 8]);
      }
#pragma unroll
      for (int n = 0; n < 4; ++n) {
        const int col = wdc * 64 + n * 16 + lc;
        const int swz = (cj & 8) | ((cj ^ col) & 7);
        bv[n] = *reinterpret_cast<const short8v*>(&W2c[col][swz * 8]);
      }
#pragma unroll
      for (int m = 0; m < 2; ++m)
#pragma unroll
        for (int n = 0; n < 4; ++n)
          oacc[m][n] = __builtin_amdgcn_mfma_f32_16x16x32_bf16(av[m], bv[n],
                                                               oacc[m][n], 0, 0, 0);
    }
    __syncthreads();
  }

  float s1l[2][4], s2l[2][4];
#pragma unroll
  for (int m = 0; m < 2; ++m) {
#pragma unroll
    for (int r = 0; r < 4; ++r) {
      const int row = M0 + wtr * 32 + m * 16 + g * 4 + r;
      float s = 0.f, s2 = 0.f;
#pragma unroll
      for (int n = 0; n < 4; ++n) {
        const int col = wdc * 64 + n * 16 + lc;
        float v = 0.f;
        if (col < 116)
          v = oacc[m][n][r] + b2[col] + res[(size_t)row * 116 + col];
        oacc[m][n][r] = v;
        s += v;
        s2 = fmaf(v, v, s2);
      }
#pragma unroll
      for (int st = 1; st < 16; st <<= 1) {
        s += __shfl_xor(s, st, 16);
        s2 += __shfl_xor(s2, st, 16);
      }
      s1l[m][r] = s;
      s2l[m][r] = s2;
    }
  }
  if (lc == 0) {
#pragma unroll
    for (int m = 0; m < 2; ++m)
#pragma unroll
      for (int r = 0; r < 4; ++r) {
        const int lrow = wtr * 32 + m * 16 + g * 4 + r;
        sum1[wdc][lrow] = s1l[m][r];
        sum2[wdc][lrow] = s2l[m][r];
      }
  }
  __syncthreads();
#pragma unroll
  for (int m = 0; m < 2; ++m) {
#pragma unroll
    for (int r = 0; r < 4; ++r) {
      const int lrow = wtr * 32 + m * 16 + g * 4 + r;
      const int row = M0 + lrow;
      const float st = sum1[0][lrow] + sum1[1][lrow];
      const float s2t = sum2[0][lrow] + sum2[1][lrow];
      const float mean = st * (1.f / 116.f);
      const float var = s2t * (1.f / 116.f) - mean * mean;
      const float rstd = 1.f / sqrtf(var + 1e-5f);
#pragma unroll
      for (int n = 0; n < 4; ++n) {
        const int col = wdc * 64 + n * 16 + lc;
        if (col < 116) {
          const float y = (oacc[m][n][r] - mean) * rstd * gw[col] + bw[col];
          Yf[(size_t)row * 116 + col] = y;
          Yb[(size_t)row * 128 + col] = f2bf(y);
        } else {
          Yb[(size_t)row * 128 + col] = 0;
        }
      }
    }
  }
}

// ---------------------------------------------------------------------------
// Attention, head-major coalesced I/O.
// ---------------------------------------------------------------------------
__global__ __launch_bounds__(64) void attn_kernel(
    const unsigned short* __restrict__ qkvp, unsigned short* __restrict__ obuf) {
  const int h = blockIdx.x & 3;
  const int n = blockIdx.x >> 2;
  const int s = threadIdx.x;
  __shared__ float ks[64][36];
  __shared__ float vs[64][36];

  const size_t rb = (((size_t)n * 4 + h) * 64 + s) * 32;
  const uint4* qp = reinterpret_cast<const uint4*>(qkvp + rb);
  const uint4* kp = reinterpret_cast<const uint4*>(qkvp + 4194304 + rb);
  const uint4* vp = reinterpret_cast<const uint4*>(qkvp + 8388608 + rb);
  uint4 qv[4], kv4[4], vv4[4];
#pragma unroll
  for (int i = 0; i < 4; ++i) {
    qv[i] = qp[i];
    kv4[i] = kp[i];
    vv4[i] = vp[i];
  }
  float q[32], kf[32], vf[32];
#pragma unroll
  for (int i = 0; i < 4; ++i) {
    const unsigned* wq = reinterpret_cast<const unsigned*>(&qv[i]);
    const unsigned* wk = reinterpret_cast<const unsigned*>(&kv4[i]);
    const unsigned* wv = reinterpret_cast<const unsigned*>(&vv4[i]);
#pragma unroll
    for (int j = 0; j < 4; ++j) {
      union { unsigned u; float f; } lo, hi;
      const int d0 = i * 8 + 2 * j;
      lo.u = wq[j] << 16; hi.u = wq[j] & 0xffff0000u;
      q[d0] = lo.f; q[d0 + 1] = hi.f;
      lo.u = wk[j] << 16; hi.u = wk[j] & 0xffff0000u;
      kf[d0] = (d0 < 29) ? lo.f : 0.f;
      kf[d0 + 1] = (d0 + 1 < 29) ? hi.f : 0.f;
      lo.u = wv[j] << 16; hi.u = wv[j] & 0xffff0000u;
      vf[d0] = (d0 < 29) ? lo.f : 0.f;
      vf[d0 + 1] = (d0 + 1 < 29) ? hi.f : 0.f;
    }
  }
  q[29] = q[30] = q[31] = 0.f;
#pragma unroll
  for (int c = 0; c < 8; ++c) {
    *reinterpret_cast<float4*>(&ks[s][c * 4]) =
        make_float4(kf[4 * c], kf[4 * c + 1], kf[4 * c + 2], kf[4 * c + 3]);
    *reinterpret_cast<float4*>(&vs[s][c * 4]) =
        make_float4(vf[4 * c], vf[4 * c + 1], vf[4 * c + 2], vf[4 * c + 3]);
  }
  __syncthreads();

  const float scale = 0.18569533817705186f;  // 1/sqrt(29)
  float sc[64];
#pragma unroll 4
  for (int t = 0; t < 64; ++t) {
    const float4* kr = reinterpret_cast<const float4*>(&ks[t][0]);
    float a = 0.f;
#pragma unroll
    for (int c = 0; c < 8; ++c) {
      const float4 kc = kr[c];
      a = fmaf(q[4 * c], kc.x, a);
      a = fmaf(q[4 * c + 1], kc.y, a);
      a = fmaf(q[4 * c + 2], kc.z, a);
      a = fmaf(q[4 * c + 3], kc.w, a);
    }
    sc[t] = a * scale;
  }
  float m = sc[0];
#pragma unroll
  for (int t = 1; t < 64; ++t) m = fmaxf(m, sc[t]);
  float sum = 0.f;
#pragma unroll
  for (int t = 0; t < 64; ++t) {
    sc[t] = __expf(sc[t] - m);
    sum += sc[t];
  }
  const float inv = 1.f / sum;
  float o[32] = {};
#pragma unroll 4
  for (int t = 0; t < 64; ++t) {
    const float p = sc[t];
    const float4* vr = reinterpret_cast<const float4*>(&vs[t][0]);
#pragma unroll
    for (int c = 0; c < 8; ++c) {
      const float4 vc = vr[c];
      o[4 * c] = fmaf(p, vc.x, o[4 * c]);
      o[4 * c + 1] = fmaf(p, vc.y, o[4 * c + 1]);
      o[4 * c + 2] = fmaf(p, vc.z, o[4 * c + 2]);
      o[4 * c + 3] = fmaf(p, vc.w, o[4 * c + 3]);
    }
  }
  unsigned short ow[32];
#pragma unroll
  for (int i = 0; i < 32; ++i) ow[i] = f2bf(o[i] * inv);
  uint4* od =
      reinterpret_cast<uint4*>(obuf + ((size_t)s * 512 + n) * 128 + h * 32);
  const uint4* ows = reinterpret_cast<const uint4*>(ow);
#pragma unroll
  for (int i = 0; i < 4; ++i) od[i] = ows[i];
}

// ---------------------------------------------------------------------------
// fc fused with feaT/fn production.
// ---------------------------------------------------------------------------
__global__ __launch_bounds__(256) void fc_kernel(
    const float* __restrict__ X4, const float* __restrict__ fw,
    const float* __restrict__ fb, float* __restrict__ fea,
    unsigned short* __restrict__ feaT, float* __restrict__ fn) {
  const int eg = blockIdx.x;  // 0..3
  const int b = blockIdx.y;   // 0..63
  const int e0 = eg * 29;
  __shared__ float Os[64][30];
  __shared__ float Wf[64][65];
  const int tid = threadIdx.x;
  const int h = tid & 63, jg = tid >> 6;
  float acc[8] = {};

  for (int tc = 0; tc < 8; ++tc) {
    for (int idx = tid; idx < 64 * 29; idx += 256) {
      int tt = idx / 29;
      int ee = idx - tt * 29;
      Os[tt][ee] = X4[((size_t)b * 512 + tc * 64 + tt) * 116 + e0 + ee];
    }
    for (int idx = tid; idx < 64 * 64; idx += 256) {
      int hh = idx >> 6, t2 = idx & 63;
      Wf[hh][t2] = fw[(size_t)hh * 512 + tc * 64 + t2];
    }
    __syncthreads();
#pragma unroll 4
    for (int t = 0; t < 64; ++t) {
      const float w = Wf[h][t];
#pragma unroll
      for (int m = 0; m < 8; ++m) {
        const int el = jg + 4 * m;
        if (el < 29) acc[m] = fmaf(Os[t][el], w, acc[m]);
      }
    }
    __syncthreads();
  }
  const float bb = fb[h];
#pragma unroll
  for (int m = 0; m < 8; ++m) {
    const int el = jg + 4 * m;
    if (el < 29) {
      const float v = acc[m] + bb;
      const int e = e0 + el;
      fea[((size_t)b * 64 + h) * 116 + e] = v;
      if (feaT) {
        const unsigned short vb = f2bf(v);
        feaT[((size_t)b * 128 + e) * 64 + h] = vb;
        float s = bf2f(vb);
        s = s * s;
#pragma unroll
        for (int st = 1; st <= 32; st <<= 1) s += __shfl_xor(s, st, 64);
        if (h == 0) fn[b * 128 + e] = sqrtf(s);
      }
    }
  }
}

// ---------------------------------------------------------------------------
// simT prep: simT[a][c(96)][h(64)] bf16, sn[a][96].
// ---------------------------------------------------------------------------
__global__ __launch_bounds__(256) void simt_prep_kernel(
    const float* __restrict__ simin, unsigned short* __restrict__ simT,
    float* __restrict__ sn) {
  __shared__ float L[64][91];
  const int a = blockIdx.x;
  const int tid = threadIdx.x;
  for (int idx = tid; idx < 64 * 90; idx += 256) {
    const int h = idx / 90, c = idx - h * 90;
    L[h][c] = bf2f(f2bf(simin[((size_t)a * 64 + h) * 90 + c]));
  }
  __syncthreads();
  for (int idx = tid; idx < 96 * 64; idx += 256) {
    const int c = idx >> 6, h = idx & 63;
    simT[((size_t)a * 96 + c) * 64 + h] = (c < 90) ? f2bf(L[h][c]) : 0;
  }
  if (tid < 90) {
    float s = 0.f;
#pragma unroll 8
    for (int h = 0; h < 64; ++h) {
      const float t = L[h][tid];
      s = fmaf(t, t, s);
    }
    sn[a * 96 + tid] = sqrtf(s);
  }
}

// ---------------------------------------------------------------------------
// Similarity v3 (best measured): block = (b, 4 consecutive a's).
// ---------------------------------------------------------------------------
__global__ __launch_bounds__(256) void sim_mfma3_kernel(
    const unsigned short* __restrict__ feaT, const unsigned short* __restrict__ simT,
    const float* __restrict__ fn, const float* __restrict__ sn,
    float* __restrict__ simil, float* __restrict__ similar) {
  const int a0 = blockIdx.x * 4;  // 0,4,...,112
  const int b = blockIdx.y;       // 0..63
  __shared__ __align__(16) unsigned short Ft[128][64];
  __shared__ __align__(16) unsigned short St[96][64];
  __shared__ __align__(16) float Rs[10440];
  __shared__ float fnrow[116];
  __shared__ float snrow[90];
  __shared__ float wred[4];
  const int tid = threadIdx.x;
  const int srow = tid >> 1, shalf = tid & 1;
  const int sw = srow & 7;
  const int wid = tid >> 6, lane = tid & 63;
  const int wr = wid >> 1, wc = wid & 1;
  const int lc = lane & 15, g = lane >> 4;

  {
    const uint4* p = reinterpret_cast<const uint4*>(
        feaT + ((size_t)b * 128 + srow) * 64 + shalf * 32);
    uint4 v0 = p[0], v1 = p[1], v2 = p[2], v3 = p[3];
    *reinterpret_cast<uint4*>(&Ft[srow][((((shalf << 2) | 0) ^ sw) << 3)]) = v0;
    *reinterpret_cast<uint4*>(&Ft[srow][((((shalf << 2) | 1) ^ sw) << 3)]) = v1;
    *reinterpret_cast<uint4*>(&Ft[srow][((((shalf << 2) | 2) ^ sw) << 3)]) = v2;
    *reinterpret_cast<uint4*>(&Ft[srow][((((shalf << 2) | 3) ^ sw) << 3)]) = v3;
  }
  if (tid < 116) fnrow[tid] = fn[b * 128 + tid];

  for (int ai = 0; ai < 4; ++ai) {
    const int a = a0 + ai;
    if (srow < 96) {
      const uint4* p = reinterpret_cast<const uint4*>(
          simT + ((size_t)a * 96 + srow) * 64 + shalf * 32);
      uint4 v0 = p[0], v1 = p[1], v2 = p[2], v3 = p[3];
      *reinterpret_cast<uint4*>(&St[srow][((((shalf << 2) | 0) ^ sw) << 3)]) = v0;
      *reinterpret_cast<uint4*>(&St[srow][((((shalf << 2) | 1) ^ sw) << 3)]) = v1;
      *reinterpret_cast<uint4*>(&St[srow][((((shalf << 2) | 2) ^ sw) << 3)]) = v2;
      *reinterpret_cast<uint4*>(&St[srow][((((shalf << 2) | 3) ^ sw) << 3)]) = v3;
    }
    if (tid >= 160 && tid < 250) snrow[tid - 160] = sn[a * 96 + (tid - 160)];
    __syncthreads();

    floatx4 acc[4][3] = {};
#pragma unroll
    for (int ks = 0; ks < 2; ++ks) {
      short8v av[4], bv[3];
#pragma unroll
      for (int m = 0; m < 4; ++m) {
        const int row = wr * 64 + m * 16 + lc;
        av[m] = *reinterpret_cast<const short8v*>(
            &Ft[row][((((ks << 2) | g) ^ (lc & 7)) << 3)]);
      }
#pragma unroll
      for (int n = 0; n < 3; ++n) {
        const int col = wc * 48 + n * 16 + lc;
        bv[n] = *reinterpret_cast<const short8v*>(
            &St[col][((((ks << 2) | g) ^ (lc & 7)) << 3)]);
      }
#pragma unroll
      for (int m = 0; m < 4; ++m)
#pragma unroll
        for (int n = 0; n < 3; ++n)
          acc[m][n] = __builtin_amdgcn_mfma_f32_16x16x32_bf16(av[m], bv[n],
                                                              acc[m][n], 0, 0, 0);
    }

    float ss = 0.f;
#pragma unroll
    for (int m = 0; m < 4; ++m) {
#pragma unroll
      for (int r = 0; r < 4; ++r) {
        const int d = wr * 64 + m * 16 + g * 4 + r;
        if (d < 116) {
          const float fnv = fnrow[d];
#pragma unroll
          for (int n = 0; n < 3; ++n) {
            const int c = wc * 48 + n * 16 + lc;
            if (c < 90) {
              const float denom = fmaxf(fnv * snrow[c], 1e-8f);
              float rcp = __builtin_amdgcn_rcpf(denom);
              rcp = rcp * (2.0f - denom * rcp);
              const float v = acc[m][n][r] * rcp;
              ss = fmaf(v, v, ss);
              Rs[d * 90 + c] = v;
            }
          }
        }
      }
    }
#pragma unroll
    for (int st = 1; st <= 32; st <<= 1) ss += __shfl_xor(ss, st, 64);
    if (lane == 0) wred[wid] = ss;
    __syncthreads();
    const float tot = wred[0] + wred[1] + wred[2] + wred[3];
    const float inv = 1.f / fmaxf(sqrtf(tot), 1e-12f);

    const size_t rowbase = ((size_t)b * 116 + a) * (116 * 90);
    float4* so = reinterpret_cast<float4*>(simil + rowbase);
    float4* sr = reinterpret_cast<float4*>(similar + rowbase);
    const float4* rs4 = reinterpret_cast<const float4*>(Rs);
    for (int i = tid; i < 2610; i += 256) {
      float4 v = rs4[i];
      so[i] = v;
      float4 w;
      w.x = v.x * inv; w.y = v.y * inv; w.z = v.z * inv; w.w = v.w * inv;
      sr[i] = w;
    }
  }
}

// ---------------------------------------------------------------------------
// Fallback similarity (self-contained) if d_ws is too small.
// ---------------------------------------------------------------------------
__global__ __launch_bounds__(256) void sim_mfma_kernel(
    const float* __restrict__ fea, const float* __restrict__ simin,
    float* __restrict__ simil, float* __restrict__ similar) {
  const int a = blockIdx.x;
  const int b = blockIdx.y;
  __shared__ __align__(16) unsigned char shmem[41760];
  __shared__ float fnrow[116];
  __shared__ float snrow[90];
  __shared__ float wred[4];
  const int tid = threadIdx.x;

  unsigned short (*Ft)[64] = reinterpret_cast<unsigned short(*)[64]>(shmem);
  unsigned short (*St)[64] =
      reinterpret_cast<unsigned short(*)[64]>(shmem + 16384);
  float* Rs = reinterpret_cast<float*>(shmem);

  for (int idx = tid; idx < 64 * 116; idx += 256) {
    const int h = idx / 116, d = idx - h * 116;
    Ft[d][(((h >> 3) ^ (d & 7)) << 3) | (h & 7)] =
        f2bf(fea[((size_t)b * 64 + h) * 116 + d]);
  }
  for (int idx = tid; idx < 12 * 64; idx += 256) {
    const int d = 116 + (idx >> 6), h = idx & 63;
    Ft[d][(((h >> 3) ^ (d & 7)) << 3) | (h & 7)] = 0;
  }
  for (int idx = tid; idx < 64 * 90; idx += 256) {
    const int h = idx / 90, c = idx - h * 90;
    St[c][(((h >> 3) ^ (c & 7)) << 3) | (h & 7)] =
        f2bf(simin[((size_t)a * 64 + h) * 90 + c]);
  }
  for (int idx = tid; idx < 6 * 64; idx += 256) {
    const int c = 90 + (idx >> 6), h = idx & 63;
    St[c][(((h >> 3) ^ (c & 7)) << 3) | (h & 7)] = 0;
  }
  __syncthreads();

  if (tid < 116) {
    float s = 0.f;
#pragma unroll 8
    for (int h = 0; h < 64; ++h) {
      const float t = bf2f(Ft[tid][(((h >> 3) ^ (tid & 7)) << 3) | (h & 7)]);
      s = fmaf(t, t, s);
    }
    fnrow[tid] = sqrtf(s);
  } else if (tid >= 128 && tid < 218) {
    const int c = tid - 128;
    float s = 0.f;
#pragma unroll 8
    for (int h = 0; h < 64; ++h) {
      const float t = bf2f(St[c][(((h >> 3) ^ (c & 7)) << 3) | (h & 7)]);
      s = fmaf(t, t, s);
    }
    snrow[c] = sqrtf(s);
  }
  __syncthreads();

  const int wid = tid >> 6, lane = tid & 63;
  const int wr = wid >> 1, wc = wid & 1;
  const int lc = lane & 15, g = lane >> 4;

  floatx4 acc[4][3] = {};
#pragma unroll
  for (int ks = 0; ks < 2; ++ks) {
    short8v av[4], bv[3];
#pragma unroll
    for (int m = 0; m < 4; ++m) {
      const int row = wr * 64 + m * 16 + lc;
      av[m] = *reinterpret_cast<const short8v*>(
          &Ft[row][((((ks << 2) | g) ^ (lc & 7)) << 3)]);
    }
#pragma unroll
    for (int n = 0; n < 3; ++n) {
      const int col = wc * 48 + n * 16 + lc;
      bv[n] = *reinterpret_cast<const short8v*>(
          &St[col][((((ks << 2) | g) ^ (lc & 7)) << 3)]);
    }
#pragma unroll
    for (int m = 0; m < 4; ++m)
#pragma unroll
      for (int n = 0; n < 3; ++n)
        acc[m][n] = __builtin_amdgcn_mfma_f32_16x16x32_bf16(av[m], bv[n],
                                                            acc[m][n], 0, 0, 0);
  }
  __syncthreads();

  float ss = 0.f;
#pragma unroll
  for (int m = 0; m < 4; ++m) {
#pragma unroll
    for (int r = 0; r < 4; ++r) {
      const int d = wr * 64 + m * 16 + g * 4 + r;
      if (d < 116) {
        const float fnv = fnrow[d];
#pragma unroll
        for (int n = 0; n < 3; ++n) {
          const int c = wc * 48 + n * 16 + lc;
          if (c < 90) {
            const float denom = fmaxf(fnv * snrow[c], 1e-8f);
            float rcp = __builtin_amdgcn_rcpf(denom);
            rcp = rcp * (2.0f - denom * rcp);
            const float v = acc[m][n][r] * rcp;
            ss = fmaf(v, v, ss);
            Rs[d * 90 + c] = v;
          }
        }
      }
    }
  }
#pragma unroll
  for (int st = 1; st <= 32; st <<= 1) ss += __shfl_xor(ss, st, 64);
  if (lane == 0) wred[wid] = ss;
  __syncthreads();
  const float tot = wred[0] + wred[1] + wred[2] + wred[3];
  const float inv = 1.f / fmaxf(sqrtf(tot), 1e-12f);

  const size_t rowbase = ((size_t)b * 116 + a) * (116 * 90);
  float4* so = reinterpret_cast<float4*>(simil + rowbase);
  float4* sr = reinterpret_cast<float4*>(similar + rowbase);
  const float4* rs4 = reinterpret_cast<const float4*>(Rs);
  for (int i = tid; i < 2610; i += 256) {
    float4 v = rs4[i];
    so[i] = v;
    float4 w;
    w.x = v.x * inv; w.y = v.y * inv; w.z = v.z * inv; w.w = v.w * inv;
    sr[i] = w;
  }
}

// ---------------------------------------------------------------------------
extern "C" void kernel_launch(void* const* d_in, const int* in_sizes, int n_in,
                              void* d_out, int out_size, void* d_ws,
                              size_t ws_size, hipStream_t stream) {
  const float* x0 = (const float*)d_in[0];
  const float* simin = (const float*)d_in[1];
  const float* p[24];
  for (int i = 0; i < 24; ++i) p[i] = (const float*)d_in[2 + i];
  const float* fc_w = (const float*)d_in[26];
  const float* fc_b = (const float*)d_in[27];

  float* out = (float*)d_out;
  float* fea = out;
  float* simil = out + 475136;       // 77,506,560 floats
  float* similar = out + 77981696;   // 475136 + 77506560

  // scratch in 'similar' region (all dead before sim writes it):
  float* xa_f[2] = {similar + 0, similar + 7602176};
  float* xb_f[2] = {similar + 3801088, similar + 11403264};
  unsigned short* obufb = (unsigned short*)(similar + 15204352);
  unsigned short* qkvp = (unsigned short*)(similar + 17301504);
  unsigned short* Ab = (unsigned short*)(similar + 23592960);
  unsigned short* xab[2] = {(unsigned short*)(similar + 25690112),
                            (unsigned short*)(similar + 29884416)};
  unsigned short* xbb[2] = {(unsigned short*)(similar + 27787264),
                            (unsigned short*)(similar + 31981568)};
  // scratch in 'simil' region:
  unsigned short* wbuf = (unsigned short*)(simil + 33554432);
  const size_t WSZ = 559104;

  // d_ws layout for sim (bytes)
  unsigned char* ws = (unsigned char*)d_ws;
  unsigned short* feaT = (unsigned short*)ws;                   // 1,048,576 B
  unsigned short* simT = (unsigned short*)(ws + 1048576);       // 1,425,408 B
  float* fnb = (float*)(ws + 2473984);
  float* snb = (float*)(ws + 2506752);
  const bool ws_ok = ws_size >= 2551296;

  {
    ConvJobs J;
    int cum = 0;
    auto add = [&](int j, const float* s, unsigned short* dd, int R, int K,
                   int Kp, int mode) {
      J.src[j] = s; J.dst[j] = dd; J.K[j] = K; J.Kp[j] = Kp; J.mode[j] = mode;
      J.cum[j] = cum; cum += R * Kp;
    };
    add(0, x0, Ab, 32768, 116, 128, 0);
    for (int L = 0; L < 2; ++L) {
      unsigned short* wb = wbuf + L * WSZ;
      add(1 + L * 4, p[L * 12 + 0], wb + 0, 348, 116, 128, 0);
      add(2 + L * 4, p[L * 12 + 2], wb + 44544, 116, 116, 128, 1);
      add(3 + L * 4, p[L * 12 + 6], wb + 59392, 2048, 116, 128, 0);
      add(4 + L * 4, p[L * 12 + 8], wb + 321536, 116, 2048, 2048, 0);
    }
    J.cum[9] = cum;
    hipLaunchKernelGGL(convert_all_kernel, dim3(2048), dim3(256), 0, stream, J);
  }

  if (ws_ok) {
    hipLaunchKernelGGL(simt_prep_kernel, dim3(116), dim3(256), 0, stream,
                       simin, simT, snb);
  }

  const unsigned short* Ain = Ab;
  const float* resin = x0;
  for (int L = 0; L < 2; ++L) {
    unsigned short* wb = wbuf + L * WSZ;
    const float* bqkv = p[L * 12 + 1];
    const float* bo = p[L * 12 + 3];
    const float* g1 = p[L * 12 + 4];
    const float* bn1 = p[L * 12 + 5];
    const float* b1 = p[L * 12 + 7];
    const float* b2 = p[L * 12 + 9];
    const float* g2 = p[L * 12 + 10];
    const float* bn2 = p[L * 12 + 11];

    hipLaunchKernelGGL(qkv_gemm_kernel, dim3(256, 3), dim3(256), 0, stream,
                       Ain, wb + 0, bqkv, qkvp);
    hipLaunchKernelGGL(attn_kernel, dim3(2048), dim3(64), 0, stream, qkvp,
                       obufb);
    hipLaunchKernelGGL(mgemm64_ln_kernel, dim3(512), dim3(256), 0, stream,
                       obufb, wb + 44544, bo, 128, xab[L], xa_f[L], resin, g1,
                       bn1);
    hipLaunchKernelGGL(ffn_fused2_kernel, dim3(256), dim3(512), 0, stream,
                       xab[L], wb + 59392, b1, wb + 321536, b2, xa_f[L], g2,
                       bn2, xbb[L], xb_f[L]);
    Ain = xbb[L];
    resin = xb_f[L];
  }

  if (ws_ok) {
    hipLaunchKernelGGL(fc_kernel, dim3(4, 64), dim3(256), 0, stream, xb_f[1],
                       fc_w, fc_b, fea, feaT, fnb);
    hipLaunchKernelGGL(sim_mfma3_kernel, dim3(29, 64), dim3(256), 0, stream,
                       feaT, simT, fnb, snb, simil, similar);
  } else {
    hipLaunchKernelGGL(fc_kernel, dim3(4, 64), dim3(256), 0, stream, xb_f[1],
                       fc_w, fc_b, fea, (unsigned short*)nullptr,
                       (float*)nullptr);
    hipLaunchKernelGGL(sim_mfma_kernel, dim3(116, 64), dim3(256), 0, stream,
                       fea, simin, simil, similar);
  }
}